// Round 1
// 1057.502 us; speedup vs baseline: 1.0995x; 1.0995x over previous
//
#include <hip/hip_runtime.h>
#include <cstdint>
#include <cstddef>

// Shapes (fixed by the problem)
#define NTOK 8192   // B*T
#define CDIM 1024
#define HDIM 2048
#define NEXP 8
#define NSEG 9        // 8 routed + 1 shared
#define MAXTILES 104  // 256-row tiles: worst case 72 routed (16384 + 8*255 padded) + 32 shared

typedef __bf16 bf16;
typedef unsigned short u16;
typedef __attribute__((ext_vector_type(8))) __bf16 bf16x8;
typedef __attribute__((ext_vector_type(4))) float f32x4;

__device__ __forceinline__ u16 f2bf(float f) {
  union { u16 u; __bf16 b; } cv;
  cv.b = (__bf16)f;
  return cv.u;
}

// Async global->LDS, 16B per lane. Global address may be per-lane arbitrary;
// LDS dest must be wave-uniform base + lane*16 (ours is lane-linear).
__device__ __forceinline__ void gload_lds16(const bf16* g, bf16* l) {
  __builtin_amdgcn_global_load_lds(
      (const __attribute__((address_space(1))) unsigned int*)g,
      (__attribute__((address_space(3))) unsigned int*)l, 16, 0, 0);
}

// ---------------- init control counters ----------------
__global__ __launch_bounds__(64) void init_kernel(int* __restrict__ counts,
                                                  int* __restrict__ fill) {
  if (threadIdx.x < NEXP) {
    counts[threadIdx.x] = 0;
    fill[threadIdx.x] = 0;
  }
}

// ---------------- zero the output accumulator ----------------
__global__ __launch_bounds__(256) void zero_out_kernel(float* __restrict__ out) {
  size_t i = ((size_t)blockIdx.x * 256 + threadIdx.x) * 8;
  float4 z = {0.f, 0.f, 0.f, 0.f};
  *(float4*)(out + i) = z;
  *(float4*)(out + i + 4) = z;
}

// ---------------- x: fp32 -> bf16 ----------------
__global__ __launch_bounds__(256) void cast_x_kernel(
    const float* __restrict__ src, bf16* __restrict__ dst) {
  size_t i = ((size_t)blockIdx.x * 256 + threadIdx.x) * 8;
  float4 a = *(const float4*)(src + i);
  float4 b = *(const float4*)(src + i + 4);
  bf16x8 p;
  p[0] = (bf16)a.x; p[1] = (bf16)a.y; p[2] = (bf16)a.z; p[3] = (bf16)a.w;
  p[4] = (bf16)b.x; p[5] = (bf16)b.y; p[6] = (bf16)b.z; p[7] = (bf16)b.w;
  *(bf16x8*)(dst + i) = p;
}

// ---------------- router: logits + top2 + per-expert counts ----------------
__global__ __launch_bounds__(256) void router2_kernel(
    const float* __restrict__ x, const float* __restrict__ gw,
    float* __restrict__ logits_out, int* __restrict__ tk_e,
    float* __restrict__ tk_w, int* __restrict__ counts) {
  int wv = threadIdx.x >> 6, l = threadIdx.x & 63;
  int t = blockIdx.x * 4 + wv;
  const float* xr = x + (size_t)t * CDIM;
  float acc[NEXP];
#pragma unroll
  for (int e = 0; e < NEXP; ++e) acc[e] = 0.f;
  for (int c = l; c < CDIM; c += 64) {
    float xv = xr[c];
    const float* g = gw + (size_t)c * NEXP;
    float4 g0 = *(const float4*)(g);
    float4 g1 = *(const float4*)(g + 4);
    acc[0] += xv * g0.x; acc[1] += xv * g0.y; acc[2] += xv * g0.z; acc[3] += xv * g0.w;
    acc[4] += xv * g1.x; acc[5] += xv * g1.y; acc[6] += xv * g1.z; acc[7] += xv * g1.w;
  }
#pragma unroll
  for (int off = 32; off > 0; off >>= 1) {
#pragma unroll
    for (int e = 0; e < NEXP; ++e) acc[e] += __shfl_xor(acc[e], off, 64);
  }
  int e0 = 0; float l0 = acc[0];
#pragma unroll
  for (int e = 1; e < NEXP; ++e) { if (acc[e] > l0) { l0 = acc[e]; e0 = e; } }
  int e1 = -1; float l1 = -3.4e38f;
#pragma unroll
  for (int e = 0; e < NEXP; ++e) { if (e != e0 && acc[e] > l1) { l1 = acc[e]; e1 = e; } }
  float ex = expf(l1 - l0);
  float w0 = 1.f / (1.f + ex), w1 = ex / (1.f + ex);
  if (l < NEXP) logits_out[(size_t)t * NEXP + l] = acc[l];
  if (l == 0) {
    tk_e[2 * t] = e0; tk_e[2 * t + 1] = e1;
    tk_w[2 * t] = w0; tk_w[2 * t + 1] = w1;
    atomicAdd(&counts[e0], 1);
    atomicAdd(&counts[e1], 1);
  }
}

// ---------------- segment offsets (pad 256), tile->segment map, pad fill ----------------
__global__ __launch_bounds__(256) void offsets_kernel(
    const int* __restrict__ counts, int* __restrict__ offs_g,
    int* __restrict__ tile_seg, int* __restrict__ list_tok,
    float* __restrict__ w_row) {
  __shared__ int off[NSEG], pad[NSEG], cnt[NSEG], ntot;
  int tid = threadIdx.x;
  if (tid == 0) {
    int tot = 0;
    for (int e = 0; e < NSEG; ++e) {
      int c = (e < NEXP) ? counts[e] : NTOK;
      cnt[e] = c; off[e] = tot;
      int p = (c + 255) & ~255;
      pad[e] = p; tot += p;
    }
    ntot = tot;
  }
  __syncthreads();
  if (tid < NSEG) offs_g[tid] = off[tid];
  for (int gt = tid; gt < MAXTILES; gt += 256) {
    int row = gt * 256, seg = -1;
    if (row < ntot) {
      for (int e = 0; e < NSEG; ++e)
        if (row >= off[e] && row < off[e] + pad[e]) { seg = e; break; }
    }
    tile_seg[gt] = seg;
  }
  for (int e = 0; e < NSEG; ++e)
    for (int i = off[e] + cnt[e] + tid; i < off[e] + pad[e]; i += 256) {
      list_tok[i] = 0;
      w_row[i] = 0.f;   // pad rows contribute nothing
    }
}

// ---------------- scatter tokens into compact lists + per-row combine weight ----------------
__global__ __launch_bounds__(256) void scatter_kernel(
    const int* __restrict__ tk_e, const float* __restrict__ tk_w,
    const int* __restrict__ offs, int* __restrict__ fill,
    int* __restrict__ list_tok, float* __restrict__ w_row) {
  int t = blockIdx.x * 256 + threadIdx.x;
  int e0 = tk_e[2 * t], e1 = tk_e[2 * t + 1];
  float w0 = tk_w[2 * t], w1 = tk_w[2 * t + 1];
  int p0 = atomicAdd(&fill[e0], 1);
  int i0 = offs[e0] + p0;
  list_tok[i0] = t; w_row[i0] = w0;
  int p1 = atomicAdd(&fill[e1], 1);
  int i1 = offs[e1] + p1;
  list_tok[i1] = t; w_row[i1] = w1;
  int rsh = offs[NEXP] + t;   // shared segment: identity, weight 1
  list_tok[rsh] = t; w_row[rsh] = 1.f;
}

// ---------------- transpose+cast body: fp32 RxC -> bf16 CxR ----------------
__device__ __forceinline__ void transpose_body(const float* __restrict__ src,
                                               u16* __restrict__ dst, int R, int C) {
  __shared__ u16 tile[64][65];
  int r0 = blockIdx.y * 64, c0 = blockIdx.x * 64;
  int tr = threadIdx.x >> 2;
  int tc = (threadIdx.x & 3) * 16;
  const float* s = src + (size_t)(r0 + tr) * C + c0 + tc;
  float4 f[4];
#pragma unroll
  for (int q = 0; q < 4; ++q) f[q] = *(const float4*)(s + q * 4);
#pragma unroll
  for (int q = 0; q < 4; ++q) {
    tile[tr][tc + q * 4 + 0] = f2bf(f[q].x);
    tile[tr][tc + q * 4 + 1] = f2bf(f[q].y);
    tile[tr][tc + q * 4 + 2] = f2bf(f[q].z);
    tile[tr][tc + q * 4 + 3] = f2bf(f[q].w);
  }
  __syncthreads();
  union { uint4 v[2]; u16 e[16]; } u;
#pragma unroll
  for (int j = 0; j < 16; ++j) u.e[j] = tile[tc + j][tr];
  u16* d = dst + (size_t)(c0 + tr) * R + r0 + tc;
  *(uint4*)d = u.v[0];
  *(uint4*)(d + 8) = u.v[1];
}

__global__ __launch_bounds__(256) void transpose_cast_kernel(
    const float* __restrict__ src, u16* __restrict__ dst, int R, int C) {
  transpose_body(src, dst, R, C);
}

// gate/up weights: (C,H) -> (H,C). z: 0=sg,1=su, 2..9=eg[e], 10..17=eu[e]
__global__ __launch_bounds__(256) void transpose_gu_kernel(
    const float* __restrict__ sg, const float* __restrict__ su,
    const float* __restrict__ eg, const float* __restrict__ eu,
    u16* __restrict__ wTg, u16* __restrict__ wTu) {
  const size_t slot = (size_t)HDIM * CDIM;
  int z = blockIdx.z;
  const float* src; u16* dst;
  if (z == 0)       { src = sg;                 dst = wTg + 8 * slot; }
  else if (z == 1)  { src = su;                 dst = wTu + 8 * slot; }
  else if (z < 10)  { src = eg + (z - 2) * slot;  dst = wTg + (z - 2) * slot; }
  else              { src = eu + (z - 10) * slot; dst = wTu + (z - 10) * slot; }
  transpose_body(src, dst, CDIM, HDIM);
}

// down weights: (H,C) -> (C,H). z: 0=sd, 1..8=ed[e]
__global__ __launch_bounds__(256) void transpose_d_kernel(
    const float* __restrict__ sd, const float* __restrict__ ed,
    u16* __restrict__ wTd) {
  const size_t slot = (size_t)HDIM * CDIM;
  int z = blockIdx.z;
  const float* src; u16* dst;
  if (z == 0) { src = sd;                 dst = wTd + 8 * slot; }
  else        { src = ed + (z - 1) * slot; dst = wTd + (z - 1) * slot; }
  transpose_body(src, dst, HDIM, CDIM);
}

// =====================================================================
// 2-phase double-buffered gather-GEMMs. 256x128 tile, BK=64, 8 waves.
// LDS XOR-swizzle applied on the GLOBAL source (dest stays lane-linear for
// global_load_lds) and on the ds_read side: col16' = col16 ^ (row & 7).
// Block order: XCD-chunked column-major (col = wid / MAXTILES).
// =====================================================================

// ---------------- fused gate+up gather-GEMM with silu epilogue ----------------
__global__ __launch_bounds__(512, 2) void gemm_gu2(
    const bf16* __restrict__ xb, const bf16* __restrict__ wTg,
    const bf16* __restrict__ wTu, const int* __restrict__ tile_seg,
    const int* __restrict__ list_tok, bf16* __restrict__ act) {
  __shared__ __align__(16) bf16 sA[2][256 * 64];
  __shared__ __align__(16) bf16 sBg[2][128 * 64];
  __shared__ __align__(16) bf16 sBu[2][128 * 64];
  __shared__ int tokLds[256];

  const int nwg = gridDim.x;                           // 16 * MAXTILES, %8 == 0
  const int bid = blockIdx.x;
  const int wid = (bid & 7) * (nwg >> 3) + (bid >> 3); // bijective XCD chunking
  const int tileIdx = wid % MAXTILES;
  const int colIdx = wid / MAXTILES;
  const int seg = tile_seg[tileIdx];
  if (seg < 0) return;

  const int tid = threadIdx.x, l = tid & 63, wv = tid >> 6;
  const int wr = wv >> 1, wc = wv & 1;                 // 4 M-waves x 2 N-waves
  const int n0 = colIdx * 128;
  const size_t rowbase = (size_t)tileIdx * 256;

  if (tid < 256) tokLds[tid] = list_tok[rowbase + tid];
  __syncthreads();

  // staging: per thread, row = q*64 + tid/8, src col pre-swizzled
  const int srow = tid >> 3;
  const int scolSw = ((tid & 7) ^ (srow & 7)) << 3;    // bf16 units
  const bf16* baseA[4];
#pragma unroll
  for (int q = 0; q < 4; ++q)
    baseA[q] = xb + (size_t)tokLds[q * 64 + srow] * CDIM + scolSw;
  const size_t wslot = (size_t)seg * HDIM * CDIM;
  const bf16* baseBg[2];
  const bf16* baseBu[2];
#pragma unroll
  for (int q = 0; q < 2; ++q) {
    const size_t r = (size_t)(n0 + q * 64 + srow) * CDIM + scolSw;
    baseBg[q] = wTg + wslot + r;
    baseBu[q] = wTu + wslot + r;
  }
  const int ldst = tid * 8;

  // fragment read offsets (bytes), swizzled: col16 = (kk*4 + l>>4) ^ (l&7)
  const int fr = l & 15;
  const int aRowB = (wr * 64 + fr) * 128;
  const int bRowB = (wc * 64 + fr) * 128;
  const int cSw0 = (((l >> 4) ^ (l & 7)) << 4);
  const int cSw1 = (((4 | (l >> 4)) ^ (l & 7)) << 4);

  f32x4 accG[4][4], accU[4][4];
#pragma unroll
  for (int i = 0; i < 4; ++i)
#pragma unroll
    for (int j = 0; j < 4; ++j) {
      accG[i][j] = (f32x4){0.f, 0.f, 0.f, 0.f};
      accU[i][j] = (f32x4){0.f, 0.f, 0.f, 0.f};
    }

  auto stage = [&](int b, int k0) {
#pragma unroll
    for (int q = 0; q < 4; ++q)
      gload_lds16(baseA[q] + k0, &sA[b][q * 4096 + ldst]);
#pragma unroll
    for (int q = 0; q < 2; ++q) {
      gload_lds16(baseBg[q] + k0, &sBg[b][q * 4096 + ldst]);
      gload_lds16(baseBu[q] + k0, &sBu[b][q * 4096 + ldst]);
    }
  };
  auto compute = [&](int b) {
    const char* pA = (const char*)&sA[b][0];
    const char* pG = (const char*)&sBg[b][0];
    const char* pU = (const char*)&sBu[b][0];
#pragma unroll
    for (int kk = 0; kk < 2; ++kk) {
      const int cSw = kk ? cSw1 : cSw0;
      bf16x8 af[4], bg[4], bu[4];
#pragma unroll
      for (int i = 0; i < 4; ++i) af[i] = *(const bf16x8*)(pA + aRowB + i * 2048 + cSw);
#pragma unroll
      for (int j = 0; j < 4; ++j) bg[j] = *(const bf16x8*)(pG + bRowB + j * 2048 + cSw);
#pragma unroll
      for (int j = 0; j < 4; ++j) bu[j] = *(const bf16x8*)(pU + bRowB + j * 2048 + cSw);
#pragma unroll
      for (int i = 0; i < 4; ++i)
#pragma unroll
        for (int j = 0; j < 4; ++j) {
          accG[i][j] = __builtin_amdgcn_mfma_f32_16x16x32_bf16(af[i], bg[j], accG[i][j], 0, 0, 0);
          accU[i][j] = __builtin_amdgcn_mfma_f32_16x16x32_bf16(af[i], bu[j], accU[i][j], 0, 0, 0);
        }
    }
  };

  const int NKT = CDIM / 64;  // 16 (even)
  stage(0, 0);
  for (int kt = 0; kt < NKT; kt += 2) {
    __syncthreads();                       // drains stage into buf0
    stage(1, (kt + 1) * 64);
    compute(0);
    __syncthreads();                       // drains stage into buf1
    if (kt + 2 < NKT) stage(0, (kt + 2) * 64);
    compute(1);
  }

  const int cn = n0 + wc * 64 + fr;
  const int rb = wr * 64 + (l >> 4) * 4;
#pragma unroll
  for (int i = 0; i < 4; ++i)
#pragma unroll
    for (int r = 0; r < 4; ++r) {
      const size_t row = rowbase + rb + i * 16 + r;
#pragma unroll
      for (int j = 0; j < 4; ++j) {
        float g = accG[i][j][r], u = accU[i][j][r];
        float s = g / (1.f + expf(-g));
        act[row * HDIM + cn + j * 16] = (bf16)(s * u);
      }
    }
}

// ---------------- down-proj GEMM with fused weighted atomic combine ----------------
__global__ __launch_bounds__(512, 2) void gemm_down2(
    const bf16* __restrict__ act, const bf16* __restrict__ wTd,
    const int* __restrict__ tile_seg, const int* __restrict__ list_tok,
    const float* __restrict__ w_row, float* __restrict__ out) {
  __shared__ __align__(16) bf16 sA[2][256 * 64];
  __shared__ __align__(16) bf16 sB[2][128 * 64];
  __shared__ int tokLds[256];
  __shared__ float wLds[256];

  const int nwg = gridDim.x;                           // 8 * MAXTILES, %8 == 0
  const int bid = blockIdx.x;
  const int wid = (bid & 7) * (nwg >> 3) + (bid >> 3);
  const int tileIdx = wid % MAXTILES;
  const int colIdx = wid / MAXTILES;
  const int seg = tile_seg[tileIdx];
  if (seg < 0) return;

  const int tid = threadIdx.x, l = tid & 63, wv = tid >> 6;
  const int wr = wv >> 1, wc = wv & 1;
  const int n0 = colIdx * 128;
  const size_t rowbase = (size_t)tileIdx * 256;

  if (tid < 256) tokLds[tid] = list_tok[rowbase + tid];
  else           wLds[tid - 256] = w_row[rowbase + tid - 256];
  __syncthreads();

  const int srow = tid >> 3;
  const int scolSw = ((tid & 7) ^ (srow & 7)) << 3;
  const bf16* baseA[4];
#pragma unroll
  for (int q = 0; q < 4; ++q)
    baseA[q] = act + (rowbase + q * 64 + srow) * HDIM + scolSw;
  const bf16* baseB[2];
#pragma unroll
  for (int q = 0; q < 2; ++q)
    baseB[q] = wTd + (size_t)seg * CDIM * HDIM + (size_t)(n0 + q * 64 + srow) * HDIM + scolSw;
  const int ldst = tid * 8;

  const int fr = l & 15;
  const int aRowB = (wr * 64 + fr) * 128;
  const int bRowB = (wc * 64 + fr) * 128;
  const int cSw0 = (((l >> 4) ^ (l & 7)) << 4);
  const int cSw1 = (((4 | (l >> 4)) ^ (l & 7)) << 4);

  f32x4 acc[4][4];
#pragma unroll
  for (int i = 0; i < 4; ++i)
#pragma unroll
    for (int j = 0; j < 4; ++j) acc[i][j] = (f32x4){0.f, 0.f, 0.f, 0.f};

  auto stage = [&](int b, int k0) {
#pragma unroll
    for (int q = 0; q < 4; ++q)
      gload_lds16(baseA[q] + k0, &sA[b][q * 4096 + ldst]);
#pragma unroll
    for (int q = 0; q < 2; ++q)
      gload_lds16(baseB[q] + k0, &sB[b][q * 4096 + ldst]);
  };
  auto compute = [&](int b) {
    const char* pA = (const char*)&sA[b][0];
    const char* pB = (const char*)&sB[b][0];
#pragma unroll
    for (int kk = 0; kk < 2; ++kk) {
      const int cSw = kk ? cSw1 : cSw0;
      bf16x8 af[4], bfr[4];
#pragma unroll
      for (int i = 0; i < 4; ++i) af[i] = *(const bf16x8*)(pA + aRowB + i * 2048 + cSw);
#pragma unroll
      for (int j = 0; j < 4; ++j) bfr[j] = *(const bf16x8*)(pB + bRowB + j * 2048 + cSw);
#pragma unroll
      for (int i = 0; i < 4; ++i)
#pragma unroll
        for (int j = 0; j < 4; ++j)
          acc[i][j] = __builtin_amdgcn_mfma_f32_16x16x32_bf16(af[i], bfr[j], acc[i][j], 0, 0, 0);
    }
  };

  const int NKT = HDIM / 64;  // 32 (even)
  stage(0, 0);
  for (int kt = 0; kt < NKT; kt += 2) {
    __syncthreads();
    stage(1, (kt + 1) * 64);
    compute(0);
    __syncthreads();
    if (kt + 2 < NKT) stage(0, (kt + 2) * 64);
    compute(1);
  }

  const int cn = n0 + wc * 64 + fr;
  const int rb = wr * 64 + (l >> 4) * 4;
#pragma unroll
  for (int i = 0; i < 4; ++i)
#pragma unroll
    for (int r = 0; r < 4; ++r) {
      const int lrow = rb + i * 16 + r;
      const float w = wLds[lrow];
      if (w != 0.f) {
        const int tok = tokLds[lrow];
        float* op = out + (size_t)tok * CDIM + cn;
#pragma unroll
        for (int j = 0; j < 4; ++j)
          atomicAdd(op + j * 16, w * acc[i][j][r]);
      }
    }
}

// ================= FALLBACK (round-2 dense path) =================
__global__ __launch_bounds__(256) void router_kernel(
    const float* __restrict__ x, const float* __restrict__ gw,
    float* __restrict__ dense_w, float* __restrict__ logits_out) {
  int wv = threadIdx.x >> 6, l = threadIdx.x & 63;
  int t = blockIdx.x * 4 + wv;
  const float* xr = x + (size_t)t * CDIM;
  float acc[NEXP];
#pragma unroll
  for (int e = 0; e < NEXP; ++e) acc[e] = 0.f;
  for (int c = l; c < CDIM; c += 64) {
    float xv = xr[c];
    const float* g = gw + (size_t)c * NEXP;
    float4 g0 = *(const float4*)(g);
    float4 g1 = *(const float4*)(g + 4);
    acc[0] += xv * g0.x; acc[1] += xv * g0.y; acc[2] += xv * g0.z; acc[3] += xv * g0.w;
    acc[4] += xv * g1.x; acc[5] += xv * g1.y; acc[6] += xv * g1.z; acc[7] += xv * g1.w;
  }
#pragma unroll
  for (int off = 32; off > 0; off >>= 1) {
#pragma unroll
    for (int e = 0; e < NEXP; ++e) acc[e] += __shfl_xor(acc[e], off, 64);
  }
  int e0 = 0; float l0 = acc[0];
#pragma unroll
  for (int e = 1; e < NEXP; ++e) { if (acc[e] > l0) { l0 = acc[e]; e0 = e; } }
  int e1 = -1; float l1 = -3.4e38f;
#pragma unroll
  for (int e = 0; e < NEXP; ++e) { if (e != e0 && acc[e] > l1) { l1 = acc[e]; e1 = e; } }
  float ex = expf(l1 - l0);
  float w0 = 1.f / (1.f + ex), w1 = ex / (1.f + ex);
  if (l < NEXP) {
    dense_w[(size_t)t * NEXP + l] = (l == e0) ? w0 : ((l == e1) ? w1 : 0.f);
    logits_out[(size_t)t * NEXP + l] = acc[l];
  }
}

template <int MODE>
__global__ __launch_bounds__(256) void gemm_bt(
    const bf16* __restrict__ A, const bf16* __restrict__ Bt,
    int K, int N,
    bf16* __restrict__ Dbf, const bf16* __restrict__ Gin,
    float* __restrict__ outAcc, const float* __restrict__ denseW, int expertId) {
  __shared__ __align__(16) bf16 sA[128 * 32];
  __shared__ __align__(16) bf16 sB[128 * 32];
  const int tid = threadIdx.x;
  const int l = tid & 63, wv = tid >> 6;
  const int wr = wv >> 1, wc = wv & 1;
  const int m0 = blockIdx.y * 128, n0 = blockIdx.x * 128;
  f32x4 acc[4][4];
#pragma unroll
  for (int i = 0; i < 4; ++i)
#pragma unroll
    for (int j = 0; j < 4; ++j) acc[i][j] = (f32x4){0.f, 0.f, 0.f, 0.f};
  const int srow = wv * 16 + (l >> 2);
  const int scol = (l & 3) * 8;
  const bf16* gA = A + (size_t)(m0 + srow) * K + scol;
  const bf16* gB = Bt + (size_t)(n0 + srow) * K + scol;
  bf16* lA = sA + srow * 32 + scol;
  bf16* lB = sB + srow * 32 + scol;
  const int fr = l & 15, fk = (l >> 4) * 8;
  const bf16* rA = sA + (size_t)(wr * 64 + fr) * 32 + fk;
  const bf16* rB = sB + (size_t)(wc * 64 + fr) * 32 + fk;
  for (int k0 = 0; k0 < K; k0 += 32) {
    __syncthreads();
    gload_lds16(gA, lA);
    gload_lds16(gA + (size_t)64 * K, lA + 64 * 32);
    gload_lds16(gB, lB);
    gload_lds16(gB + (size_t)64 * K, lB + 64 * 32);
    gA += 32; gB += 32;
    __syncthreads();
    bf16x8 af[4], bfr[4];
#pragma unroll
    for (int i = 0; i < 4; ++i) af[i] = *(const bf16x8*)(rA + i * 16 * 32);
#pragma unroll
    for (int j = 0; j < 4; ++j) bfr[j] = *(const bf16x8*)(rB + j * 16 * 32);
#pragma unroll
    for (int i = 0; i < 4; ++i)
#pragma unroll
      for (int j = 0; j < 4; ++j)
        acc[i][j] = __builtin_amdgcn_mfma_f32_16x16x32_bf16(af[i], bfr[j], acc[i][j], 0, 0, 0);
  }
  const int cn = n0 + wc * 64 + (l & 15);
  const int rb = m0 + wr * 64 + (l >> 4) * 4;
#pragma unroll
  for (int i = 0; i < 4; ++i)
#pragma unroll
    for (int r = 0; r < 4; ++r) {
      const int m = rb + i * 16 + r;
#pragma unroll
      for (int j = 0; j < 4; ++j) {
        const int n = cn + j * 16;
        float v = acc[i][j][r];
        if (MODE == 0) {
          Dbf[(size_t)m * N + n] = (bf16)v;
        } else if (MODE == 1) {
          float g = (float)Gin[(size_t)m * N + n];
          float s = g / (1.f + expf(-g));
          Dbf[(size_t)m * N + n] = (bf16)(s * v);
        } else if (MODE == 2) {
          outAcc[(size_t)m * N + n] = v;
        } else {
          float w = denseW[(size_t)m * NEXP + expertId];
          outAcc[(size_t)m * N + n] += w * v;
        }
      }
    }
}

extern "C" void kernel_launch(void* const* d_in, const int* in_sizes, int n_in,
                              void* d_out, int out_size, void* d_ws, size_t ws_size,
                              hipStream_t stream) {
  const float* x    = (const float*)d_in[0];
  const float* gate = (const float*)d_in[1];
  const float* sg   = (const float*)d_in[2];
  const float* su   = (const float*)d_in[3];
  const float* sd   = (const float*)d_in[4];
  const float* eg   = (const float*)d_in[5];
  const float* eu   = (const float*)d_in[6];
  const float* ed   = (const float*)d_in[7];
  float* out    = (float*)d_out;
  float* logits = out + (size_t)NTOK * CDIM;

  const size_t MB = 1u << 20;
  const size_t full_need = 226 * MB;

  if (ws_size >= full_need) {
    // ===== sparse top-2 path =====
    char* ws = (char*)d_ws;
    bf16*  xb   = (bf16*)(ws);                    // 16 MB
    bf16*  wTg  = (bf16*)(ws + 16 * MB);          // 36 MB (dead after gemm_gu2)
    bf16*  wTu  = (bf16*)(ws + 52 * MB);          // 36 MB (dead after gemm_gu2)
    bf16*  act  = (bf16*)(ws + 88 * MB);          // 104 MB (26624 x 2048 bf16)
    bf16*  wTd  = (bf16*)(ws + 16 * MB);          // aliases wTg (transposed after gemm_gu2)
    char*  sm   = ws + 224 * MB;
    int*   list_tok = (int*)(sm);                       // 104 KB
    int*   tk_e     = (int*)(sm + 256 * 1024);          // 64 KB
    float* tk_w     = (float*)(sm + 320 * 1024);        // 64 KB
    int*   tile_seg = (int*)(sm + 384 * 1024);          // 416 B
    int*   counts   = (int*)(sm + 388 * 1024);
    int*   fill     = (int*)(sm + 389 * 1024);
    int*   offs     = (int*)(sm + 390 * 1024);
    float* w_row    = (float*)(sm + 400 * 1024);        // 104 KB

    init_kernel<<<1, 64, 0, stream>>>(counts, fill);
    zero_out_kernel<<<NTOK * CDIM / (256 * 8), 256, 0, stream>>>(out);
    cast_x_kernel<<<NTOK * CDIM / (256 * 8), 256, 0, stream>>>(x, xb);
    router2_kernel<<<NTOK / 4, 256, 0, stream>>>(x, gate, logits, tk_e, tk_w, counts);
    offsets_kernel<<<1, 256, 0, stream>>>(counts, offs, tile_seg, list_tok, w_row);
    scatter_kernel<<<NTOK / 256, 256, 0, stream>>>(tk_e, tk_w, offs, fill, list_tok, w_row);

    dim3 tgu(HDIM / 64, CDIM / 64, 18);
    transpose_gu_kernel<<<tgu, 256, 0, stream>>>(sg, su, eg, eu, (u16*)wTg, (u16*)wTu);

    gemm_gu2<<<(HDIM / 128) * MAXTILES, 512, 0, stream>>>(xb, wTg, wTu, tile_seg, list_tok, act);

    dim3 tdd(CDIM / 64, HDIM / 64, 9);
    transpose_d_kernel<<<tdd, 256, 0, stream>>>(sd, ed, (u16*)wTd);

    gemm_down2<<<(CDIM / 128) * MAXTILES, 512, 0, stream>>>(act, wTd, tile_seg, list_tok, w_row, out);
    return;
  }

  // ===== fallback: round-2 dense path (requires ~61 MB) =====
  char* ws = (char*)d_ws;
  bf16*  xb   = (bf16*)(ws);
  bf16*  wTgf = (bf16*)(ws + 16 * MB);
  bf16*  wTuf = (bf16*)(ws + 20 * MB);
  bf16*  wTdf = (bf16*)(ws + 24 * MB);
  bf16*  gbuf = (bf16*)(ws + 28 * MB);
  float* dw   = (float*)(ws + 60 * MB);
  if (ws_size < 60 * MB + (size_t)NTOK * NEXP * sizeof(float)) return;

  cast_x_kernel<<<NTOK * CDIM / (256 * 8), 256, 0, stream>>>(x, xb);
  router_kernel<<<NTOK / 4, 256, 0, stream>>>(x, gate, dw, logits);

  dim3 tg1(HDIM / 64, CDIM / 64);
  dim3 tg2(CDIM / 64, HDIM / 64);
  dim3 g1(HDIM / 128, NTOK / 128);
  dim3 g2(CDIM / 128, NTOK / 128);

  transpose_cast_kernel<<<tg1, 256, 0, stream>>>(sg, (u16*)wTgf, CDIM, HDIM);
  transpose_cast_kernel<<<tg1, 256, 0, stream>>>(su, (u16*)wTuf, CDIM, HDIM);
  transpose_cast_kernel<<<tg2, 256, 0, stream>>>(sd, (u16*)wTdf, HDIM, CDIM);
  gemm_bt<0><<<g1, 256, 0, stream>>>(xb, wTgf, CDIM, HDIM, gbuf, nullptr, nullptr, nullptr, 0);
  gemm_bt<1><<<g1, 256, 0, stream>>>(xb, wTuf, CDIM, HDIM, gbuf, gbuf, nullptr, nullptr, 0);
  gemm_bt<2><<<g2, 256, 0, stream>>>(gbuf, wTdf, HDIM, CDIM, nullptr, nullptr, out, nullptr, 0);

  for (int e = 0; e < NEXP; ++e) {
    const float* egp = eg + (size_t)e * CDIM * HDIM;
    const float* eup = eu + (size_t)e * CDIM * HDIM;
    const float* edp = ed + (size_t)e * HDIM * CDIM;
    transpose_cast_kernel<<<tg1, 256, 0, stream>>>(egp, (u16*)wTgf, CDIM, HDIM);
    transpose_cast_kernel<<<tg1, 256, 0, stream>>>(eup, (u16*)wTuf, CDIM, HDIM);
    transpose_cast_kernel<<<tg2, 256, 0, stream>>>(edp, (u16*)wTdf, HDIM, CDIM);
    gemm_bt<0><<<g1, 256, 0, stream>>>(xb, wTgf, CDIM, HDIM, gbuf, nullptr, nullptr, nullptr, 0);
    gemm_bt<1><<<g1, 256, 0, stream>>>(xb, wTuf, CDIM, HDIM, gbuf, gbuf, nullptr, nullptr, 0);
    gemm_bt<3><<<g2, 256, 0, stream>>>(gbuf, wTdf, HDIM, CDIM, nullptr, nullptr, out, dw, e);
  }
}

// Round 2
// 971.490 us; speedup vs baseline: 1.1968x; 1.0885x over previous
//
#include <hip/hip_runtime.h>
#include <cstdint>
#include <cstddef>

// Shapes (fixed by the problem)
#define NTOK 8192   // B*T
#define CDIM 1024
#define HDIM 2048
#define NEXP 8
#define NSEG 9        // 8 routed + 1 shared
#define MAXTILES 104  // 256-row tiles: worst case 72 routed (16384 + 8*255 padded) + 32 shared

typedef __bf16 bf16;
typedef unsigned short u16;
typedef __attribute__((ext_vector_type(8))) __bf16 bf16x8;
typedef __attribute__((ext_vector_type(4))) float f32x4;

__device__ __forceinline__ u16 f2bf(float f) {
  union { u16 u; __bf16 b; } cv;
  cv.b = (__bf16)f;
  return cv.u;
}

// Async global->LDS, 16B per lane. Global address may be per-lane arbitrary;
// LDS dest must be wave-uniform base + lane*16 (ours is lane-linear).
__device__ __forceinline__ void gload_lds16(const bf16* g, bf16* l) {
  __builtin_amdgcn_global_load_lds(
      (const __attribute__((address_space(1))) unsigned int*)g,
      (__attribute__((address_space(3))) unsigned int*)l, 16, 0, 0);
}

// ---------------- init control counters ----------------
__global__ __launch_bounds__(64) void init_kernel(int* __restrict__ counts,
                                                  int* __restrict__ fill) {
  if (threadIdx.x < NEXP) {
    counts[threadIdx.x] = 0;
    fill[threadIdx.x] = 0;
  }
}

// ---------------- zero the output accumulator ----------------
__global__ __launch_bounds__(256) void zero_out_kernel(float* __restrict__ out) {
  size_t i = ((size_t)blockIdx.x * 256 + threadIdx.x) * 8;
  float4 z = {0.f, 0.f, 0.f, 0.f};
  *(float4*)(out + i) = z;
  *(float4*)(out + i + 4) = z;
}

// ---------------- x: fp32 -> bf16 ----------------
__global__ __launch_bounds__(256) void cast_x_kernel(
    const float* __restrict__ src, bf16* __restrict__ dst) {
  size_t i = ((size_t)blockIdx.x * 256 + threadIdx.x) * 8;
  float4 a = *(const float4*)(src + i);
  float4 b = *(const float4*)(src + i + 4);
  bf16x8 p;
  p[0] = (bf16)a.x; p[1] = (bf16)a.y; p[2] = (bf16)a.z; p[3] = (bf16)a.w;
  p[4] = (bf16)b.x; p[5] = (bf16)b.y; p[6] = (bf16)b.z; p[7] = (bf16)b.w;
  *(bf16x8*)(dst + i) = p;
}

// ---------------- router: logits + top2 + per-expert counts ----------------
__global__ __launch_bounds__(256) void router2_kernel(
    const float* __restrict__ x, const float* __restrict__ gw,
    float* __restrict__ logits_out, int* __restrict__ tk_e,
    float* __restrict__ tk_w, int* __restrict__ counts) {
  int wv = threadIdx.x >> 6, l = threadIdx.x & 63;
  int t = blockIdx.x * 4 + wv;
  const float* xr = x + (size_t)t * CDIM;
  float acc[NEXP];
#pragma unroll
  for (int e = 0; e < NEXP; ++e) acc[e] = 0.f;
  for (int c = l; c < CDIM; c += 64) {
    float xv = xr[c];
    const float* g = gw + (size_t)c * NEXP;
    float4 g0 = *(const float4*)(g);
    float4 g1 = *(const float4*)(g + 4);
    acc[0] += xv * g0.x; acc[1] += xv * g0.y; acc[2] += xv * g0.z; acc[3] += xv * g0.w;
    acc[4] += xv * g1.x; acc[5] += xv * g1.y; acc[6] += xv * g1.z; acc[7] += xv * g1.w;
  }
#pragma unroll
  for (int off = 32; off > 0; off >>= 1) {
#pragma unroll
    for (int e = 0; e < NEXP; ++e) acc[e] += __shfl_xor(acc[e], off, 64);
  }
  int e0 = 0; float l0 = acc[0];
#pragma unroll
  for (int e = 1; e < NEXP; ++e) { if (acc[e] > l0) { l0 = acc[e]; e0 = e; } }
  int e1 = -1; float l1 = -3.4e38f;
#pragma unroll
  for (int e = 0; e < NEXP; ++e) { if (e != e0 && acc[e] > l1) { l1 = acc[e]; e1 = e; } }
  float ex = expf(l1 - l0);
  float w0 = 1.f / (1.f + ex), w1 = ex / (1.f + ex);
  if (l < NEXP) logits_out[(size_t)t * NEXP + l] = acc[l];
  if (l == 0) {
    tk_e[2 * t] = e0; tk_e[2 * t + 1] = e1;
    tk_w[2 * t] = w0; tk_w[2 * t + 1] = w1;
    atomicAdd(&counts[e0], 1);
    atomicAdd(&counts[e1], 1);
  }
}

// ---------------- segment offsets (pad 256), tile->segment map, pad fill ----------------
__global__ __launch_bounds__(256) void offsets_kernel(
    const int* __restrict__ counts, int* __restrict__ offs_g,
    int* __restrict__ tile_seg, int* __restrict__ list_tok,
    float* __restrict__ w_row) {
  __shared__ int off[NSEG], pad[NSEG], cnt[NSEG], ntot;
  int tid = threadIdx.x;
  if (tid == 0) {
    int tot = 0;
    for (int e = 0; e < NSEG; ++e) {
      int c = (e < NEXP) ? counts[e] : NTOK;
      cnt[e] = c; off[e] = tot;
      int p = (c + 255) & ~255;
      pad[e] = p; tot += p;
    }
    ntot = tot;
  }
  __syncthreads();
  if (tid < NSEG) offs_g[tid] = off[tid];
  for (int gt = tid; gt < MAXTILES; gt += 256) {
    int row = gt * 256, seg = -1;
    if (row < ntot) {
      for (int e = 0; e < NSEG; ++e)
        if (row >= off[e] && row < off[e] + pad[e]) { seg = e; break; }
    }
    tile_seg[gt] = seg;
  }
  for (int e = 0; e < NSEG; ++e)
    for (int i = off[e] + cnt[e] + tid; i < off[e] + pad[e]; i += 256) {
      list_tok[i] = 0;
      w_row[i] = 0.f;   // pad rows contribute nothing
    }
}

// ---------------- scatter tokens into compact lists + per-row combine weight ----------------
__global__ __launch_bounds__(256) void scatter_kernel(
    const int* __restrict__ tk_e, const float* __restrict__ tk_w,
    const int* __restrict__ offs, int* __restrict__ fill,
    int* __restrict__ list_tok, float* __restrict__ w_row) {
  int t = blockIdx.x * 256 + threadIdx.x;
  int e0 = tk_e[2 * t], e1 = tk_e[2 * t + 1];
  float w0 = tk_w[2 * t], w1 = tk_w[2 * t + 1];
  int p0 = atomicAdd(&fill[e0], 1);
  int i0 = offs[e0] + p0;
  list_tok[i0] = t; w_row[i0] = w0;
  int p1 = atomicAdd(&fill[e1], 1);
  int i1 = offs[e1] + p1;
  list_tok[i1] = t; w_row[i1] = w1;
  int rsh = offs[NEXP] + t;   // shared segment: identity, weight 1
  list_tok[rsh] = t; w_row[rsh] = 1.f;
}

// ---------------- transpose+cast body: fp32 RxC -> bf16 CxR ----------------
__device__ __forceinline__ void transpose_body(const float* __restrict__ src,
                                               u16* __restrict__ dst, int R, int C) {
  __shared__ u16 tile[64][65];
  int r0 = blockIdx.y * 64, c0 = blockIdx.x * 64;
  int tr = threadIdx.x >> 2;
  int tc = (threadIdx.x & 3) * 16;
  const float* s = src + (size_t)(r0 + tr) * C + c0 + tc;
  float4 f[4];
#pragma unroll
  for (int q = 0; q < 4; ++q) f[q] = *(const float4*)(s + q * 4);
#pragma unroll
  for (int q = 0; q < 4; ++q) {
    tile[tr][tc + q * 4 + 0] = f2bf(f[q].x);
    tile[tr][tc + q * 4 + 1] = f2bf(f[q].y);
    tile[tr][tc + q * 4 + 2] = f2bf(f[q].z);
    tile[tr][tc + q * 4 + 3] = f2bf(f[q].w);
  }
  __syncthreads();
  union { uint4 v[2]; u16 e[16]; } u;
#pragma unroll
  for (int j = 0; j < 16; ++j) u.e[j] = tile[tc + j][tr];
  u16* d = dst + (size_t)(c0 + tr) * R + r0 + tc;
  *(uint4*)d = u.v[0];
  *(uint4*)(d + 8) = u.v[1];
}

__global__ __launch_bounds__(256) void transpose_cast_kernel(
    const float* __restrict__ src, u16* __restrict__ dst, int R, int C) {
  transpose_body(src, dst, R, C);
}

// gate/up weights: (C,H) -> (H,C). z: 0=sg,1=su, 2..9=eg[e], 10..17=eu[e]
__global__ __launch_bounds__(256) void transpose_gu_kernel(
    const float* __restrict__ sg, const float* __restrict__ su,
    const float* __restrict__ eg, const float* __restrict__ eu,
    u16* __restrict__ wTg, u16* __restrict__ wTu) {
  const size_t slot = (size_t)HDIM * CDIM;
  int z = blockIdx.z;
  const float* src; u16* dst;
  if (z == 0)       { src = sg;                 dst = wTg + 8 * slot; }
  else if (z == 1)  { src = su;                 dst = wTu + 8 * slot; }
  else if (z < 10)  { src = eg + (z - 2) * slot;  dst = wTg + (z - 2) * slot; }
  else              { src = eu + (z - 10) * slot; dst = wTu + (z - 10) * slot; }
  transpose_body(src, dst, CDIM, HDIM);
}

// down weights: (H,C) -> (C,H). z: 0=sd, 1..8=ed[e]
__global__ __launch_bounds__(256) void transpose_d_kernel(
    const float* __restrict__ sd, const float* __restrict__ ed,
    u16* __restrict__ wTd) {
  const size_t slot = (size_t)HDIM * CDIM;
  int z = blockIdx.z;
  const float* src; u16* dst;
  if (z == 0) { src = sd;                 dst = wTd + 8 * slot; }
  else        { src = ed + (z - 1) * slot; dst = wTd + (z - 1) * slot; }
  transpose_body(src, dst, HDIM, CDIM);
}

// =====================================================================
// Counted-vmcnt double-buffered gather-GEMMs. 256x128 tile, BK=64, 8 waves.
// Pipeline: two stages in flight; per K-tile:
//   s_waitcnt vmcnt(N)  (N = loads of the younger stage; NEVER 0 mid-loop)
//   s_barrier            (raw -- no implicit drain)
//   ds_read all frags; lgkmcnt(0); s_barrier   (all waves done reading buf)
//   issue stage(b, kt+2)                       (safe overwrite)
//   setprio(1); MFMA cluster; setprio(0)
// LDS XOR-swizzle on global source + ds_read side (dest lane-linear).
// =====================================================================

// ---------------- fused gate+up gather-GEMM with silu epilogue ----------------
__global__ __launch_bounds__(512, 2) void gemm_gu2(
    const bf16* __restrict__ xb, const bf16* __restrict__ wTg,
    const bf16* __restrict__ wTu, const int* __restrict__ tile_seg,
    const int* __restrict__ list_tok, bf16* __restrict__ act) {
  __shared__ __align__(16) bf16 sA[2][256 * 64];
  __shared__ __align__(16) bf16 sBg[2][128 * 64];
  __shared__ __align__(16) bf16 sBu[2][128 * 64];
  __shared__ int tokLds[256];

  const int nwg = gridDim.x;                           // 16 * MAXTILES, %8 == 0
  const int bid = blockIdx.x;
  const int wid = (bid & 7) * (nwg >> 3) + (bid >> 3); // bijective XCD chunking
  const int tileIdx = wid % MAXTILES;
  const int colIdx = wid / MAXTILES;
  const int seg = tile_seg[tileIdx];
  if (seg < 0) return;

  const int tid = threadIdx.x, l = tid & 63, wv = tid >> 6;
  const int wr = wv >> 1, wc = wv & 1;                 // 4 M-waves x 2 N-waves
  const int n0 = colIdx * 128;
  const size_t rowbase = (size_t)tileIdx * 256;

  if (tid < 256) tokLds[tid] = list_tok[rowbase + tid];
  __syncthreads();

  // staging: per thread, row = q*64 + tid/8, src col pre-swizzled
  const int srow = tid >> 3;
  const int scolSw = ((tid & 7) ^ (srow & 7)) << 3;    // bf16 units
  const bf16* baseA[4];
#pragma unroll
  for (int q = 0; q < 4; ++q)
    baseA[q] = xb + (size_t)tokLds[q * 64 + srow] * CDIM + scolSw;
  const size_t wslot = (size_t)seg * HDIM * CDIM;
  const bf16* baseBg[2];
  const bf16* baseBu[2];
#pragma unroll
  for (int q = 0; q < 2; ++q) {
    const size_t r = (size_t)(n0 + q * 64 + srow) * CDIM + scolSw;
    baseBg[q] = wTg + wslot + r;
    baseBu[q] = wTu + wslot + r;
  }
  const int ldst = tid * 8;

  // fragment read offsets (bytes), swizzled: col16 = (kk*4 + l>>4) ^ (l&7)
  const int fr = l & 15;
  const int aRowB = (wr * 64 + fr) * 128;
  const int bRowB = (wc * 64 + fr) * 128;
  const int cSw0 = (((l >> 4) ^ (l & 7)) << 4);
  const int cSw1 = (((4 | (l >> 4)) ^ (l & 7)) << 4);

  f32x4 accG[4][4], accU[4][4];
#pragma unroll
  for (int i = 0; i < 4; ++i)
#pragma unroll
    for (int j = 0; j < 4; ++j) {
      accG[i][j] = (f32x4){0.f, 0.f, 0.f, 0.f};
      accU[i][j] = (f32x4){0.f, 0.f, 0.f, 0.f};
    }

  auto stage = [&](int b, int k0) {
#pragma unroll
    for (int q = 0; q < 4; ++q)
      gload_lds16(baseA[q] + k0, &sA[b][q * 4096 + ldst]);
#pragma unroll
    for (int q = 0; q < 2; ++q) {
      gload_lds16(baseBg[q] + k0, &sBg[b][q * 4096 + ldst]);
      gload_lds16(baseBu[q] + k0, &sBu[b][q * 4096 + ldst]);
    }
  };

  constexpr int NKT = CDIM / 64;  // 16

  auto tile_step = [&](int b, int ktile, bool last) {
    if (last) asm volatile("s_waitcnt vmcnt(0)" ::: "memory");
    else      asm volatile("s_waitcnt vmcnt(8)" ::: "memory");
    __builtin_amdgcn_s_barrier();
    const char* pA = (const char*)&sA[b][0];
    const char* pG = (const char*)&sBg[b][0];
    const char* pU = (const char*)&sBu[b][0];
    bf16x8 af0[4], bg0[4], bu0[4];
#pragma unroll
    for (int i = 0; i < 4; ++i) af0[i] = *(const bf16x8*)(pA + aRowB + i * 2048 + cSw0);
#pragma unroll
    for (int j = 0; j < 4; ++j) bg0[j] = *(const bf16x8*)(pG + bRowB + j * 2048 + cSw0);
#pragma unroll
    for (int j = 0; j < 4; ++j) bu0[j] = *(const bf16x8*)(pU + bRowB + j * 2048 + cSw0);
    __builtin_amdgcn_s_setprio(1);
#pragma unroll
    for (int i = 0; i < 4; ++i)
#pragma unroll
      for (int j = 0; j < 4; ++j) {
        accG[i][j] = __builtin_amdgcn_mfma_f32_16x16x32_bf16(af0[i], bg0[j], accG[i][j], 0, 0, 0);
        accU[i][j] = __builtin_amdgcn_mfma_f32_16x16x32_bf16(af0[i], bu0[j], accU[i][j], 0, 0, 0);
      }
    __builtin_amdgcn_s_setprio(0);
    bf16x8 af1[4], bg1[4], bu1[4];
#pragma unroll
    for (int i = 0; i < 4; ++i) af1[i] = *(const bf16x8*)(pA + aRowB + i * 2048 + cSw1);
#pragma unroll
    for (int j = 0; j < 4; ++j) bg1[j] = *(const bf16x8*)(pG + bRowB + j * 2048 + cSw1);
#pragma unroll
    for (int j = 0; j < 4; ++j) bu1[j] = *(const bf16x8*)(pU + bRowB + j * 2048 + cSw1);
    asm volatile("s_waitcnt lgkmcnt(0)" ::: "memory");
    __builtin_amdgcn_s_barrier();
    if (ktile + 2 < NKT) stage(b, (ktile + 2) * 64);
    __builtin_amdgcn_s_setprio(1);
#pragma unroll
    for (int i = 0; i < 4; ++i)
#pragma unroll
      for (int j = 0; j < 4; ++j) {
        accG[i][j] = __builtin_amdgcn_mfma_f32_16x16x32_bf16(af1[i], bg1[j], accG[i][j], 0, 0, 0);
        accU[i][j] = __builtin_amdgcn_mfma_f32_16x16x32_bf16(af1[i], bu1[j], accU[i][j], 0, 0, 0);
      }
    __builtin_amdgcn_s_setprio(0);
  };

  stage(0, 0);
  stage(1, 64);
  for (int kt = 0; kt + 2 < NKT; kt += 2) {
    tile_step(0, kt, false);
    tile_step(1, kt + 1, false);
  }
  tile_step(0, NKT - 2, false);
  tile_step(1, NKT - 1, true);

  const int cn = n0 + wc * 64 + fr;
  const int rb = wr * 64 + (l >> 4) * 4;
#pragma unroll
  for (int i = 0; i < 4; ++i)
#pragma unroll
    for (int r = 0; r < 4; ++r) {
      const size_t row = rowbase + rb + i * 16 + r;
#pragma unroll
      for (int j = 0; j < 4; ++j) {
        float g = accG[i][j][r], u = accU[i][j][r];
        float s = g / (1.f + expf(-g));
        act[row * HDIM + cn + j * 16] = (bf16)(s * u);
      }
    }
}

// ---------------- down-proj GEMM with fused weighted atomic combine ----------------
__global__ __launch_bounds__(512, 2) void gemm_down2(
    const bf16* __restrict__ act, const bf16* __restrict__ wTd,
    const int* __restrict__ tile_seg, const int* __restrict__ list_tok,
    const float* __restrict__ w_row, float* __restrict__ out) {
  __shared__ __align__(16) bf16 sA[2][256 * 64];
  __shared__ __align__(16) bf16 sB[2][128 * 64];
  __shared__ int tokLds[256];
  __shared__ float wLds[256];

  const int nwg = gridDim.x;                           // 8 * MAXTILES, %8 == 0
  const int bid = blockIdx.x;
  const int wid = (bid & 7) * (nwg >> 3) + (bid >> 3);
  const int tileIdx = wid % MAXTILES;
  const int colIdx = wid / MAXTILES;
  const int seg = tile_seg[tileIdx];
  if (seg < 0) return;

  const int tid = threadIdx.x, l = tid & 63, wv = tid >> 6;
  const int wr = wv >> 1, wc = wv & 1;
  const int n0 = colIdx * 128;
  const size_t rowbase = (size_t)tileIdx * 256;

  if (tid < 256) tokLds[tid] = list_tok[rowbase + tid];
  else           wLds[tid - 256] = w_row[rowbase + tid - 256];
  __syncthreads();

  const int srow = tid >> 3;
  const int scolSw = ((tid & 7) ^ (srow & 7)) << 3;
  const bf16* baseA[4];
#pragma unroll
  for (int q = 0; q < 4; ++q)
    baseA[q] = act + (rowbase + q * 64 + srow) * HDIM + scolSw;
  const bf16* baseB[2];
#pragma unroll
  for (int q = 0; q < 2; ++q)
    baseB[q] = wTd + (size_t)seg * CDIM * HDIM + (size_t)(n0 + q * 64 + srow) * HDIM + scolSw;
  const int ldst = tid * 8;

  const int fr = l & 15;
  const int aRowB = (wr * 64 + fr) * 128;
  const int bRowB = (wc * 64 + fr) * 128;
  const int cSw0 = (((l >> 4) ^ (l & 7)) << 4);
  const int cSw1 = (((4 | (l >> 4)) ^ (l & 7)) << 4);

  f32x4 acc[4][4];
#pragma unroll
  for (int i = 0; i < 4; ++i)
#pragma unroll
    for (int j = 0; j < 4; ++j) acc[i][j] = (f32x4){0.f, 0.f, 0.f, 0.f};

  auto stage = [&](int b, int k0) {
#pragma unroll
    for (int q = 0; q < 4; ++q)
      gload_lds16(baseA[q] + k0, &sA[b][q * 4096 + ldst]);
#pragma unroll
    for (int q = 0; q < 2; ++q)
      gload_lds16(baseB[q] + k0, &sB[b][q * 4096 + ldst]);
  };

  constexpr int NKT = HDIM / 64;  // 32

  auto tile_step = [&](int b, int ktile, bool last) {
    if (last) asm volatile("s_waitcnt vmcnt(0)" ::: "memory");
    else      asm volatile("s_waitcnt vmcnt(6)" ::: "memory");
    __builtin_amdgcn_s_barrier();
    const char* pA = (const char*)&sA[b][0];
    const char* pB = (const char*)&sB[b][0];
    bf16x8 af0[4], bf0[4];
#pragma unroll
    for (int i = 0; i < 4; ++i) af0[i] = *(const bf16x8*)(pA + aRowB + i * 2048 + cSw0);
#pragma unroll
    for (int j = 0; j < 4; ++j) bf0[j] = *(const bf16x8*)(pB + bRowB + j * 2048 + cSw0);
    __builtin_amdgcn_s_setprio(1);
#pragma unroll
    for (int i = 0; i < 4; ++i)
#pragma unroll
      for (int j = 0; j < 4; ++j)
        acc[i][j] = __builtin_amdgcn_mfma_f32_16x16x32_bf16(af0[i], bf0[j], acc[i][j], 0, 0, 0);
    __builtin_amdgcn_s_setprio(0);
    bf16x8 af1[4], bf1[4];
#pragma unroll
    for (int i = 0; i < 4; ++i) af1[i] = *(const bf16x8*)(pA + aRowB + i * 2048 + cSw1);
#pragma unroll
    for (int j = 0; j < 4; ++j) bf1[j] = *(const bf16x8*)(pB + bRowB + j * 2048 + cSw1);
    asm volatile("s_waitcnt lgkmcnt(0)" ::: "memory");
    __builtin_amdgcn_s_barrier();
    if (ktile + 2 < NKT) stage(b, (ktile + 2) * 64);
    __builtin_amdgcn_s_setprio(1);
#pragma unroll
    for (int i = 0; i < 4; ++i)
#pragma unroll
      for (int j = 0; j < 4; ++j)
        acc[i][j] = __builtin_amdgcn_mfma_f32_16x16x32_bf16(af1[i], bf1[j], acc[i][j], 0, 0, 0);
    __builtin_amdgcn_s_setprio(0);
  };

  stage(0, 0);
  stage(1, 64);
  for (int kt = 0; kt + 2 < NKT; kt += 2) {
    tile_step(0, kt, false);
    tile_step(1, kt + 1, false);
  }
  tile_step(0, NKT - 2, false);
  tile_step(1, NKT - 1, true);

  const int cn = n0 + wc * 64 + fr;
  const int rb = wr * 64 + (l >> 4) * 4;
#pragma unroll
  for (int i = 0; i < 4; ++i)
#pragma unroll
    for (int r = 0; r < 4; ++r) {
      const int lrow = rb + i * 16 + r;
      const float w = wLds[lrow];
      if (w != 0.f) {
        const int tok = tokLds[lrow];
        float* op = out + (size_t)tok * CDIM + cn;
#pragma unroll
        for (int j = 0; j < 4; ++j)
          atomicAdd(op + j * 16, w * acc[i][j][r]);
      }
    }
}

// ================= FALLBACK (round-2 dense path) =================
__global__ __launch_bounds__(256) void router_kernel(
    const float* __restrict__ x, const float* __restrict__ gw,
    float* __restrict__ dense_w, float* __restrict__ logits_out) {
  int wv = threadIdx.x >> 6, l = threadIdx.x & 63;
  int t = blockIdx.x * 4 + wv;
  const float* xr = x + (size_t)t * CDIM;
  float acc[NEXP];
#pragma unroll
  for (int e = 0; e < NEXP; ++e) acc[e] = 0.f;
  for (int c = l; c < CDIM; c += 64) {
    float xv = xr[c];
    const float* g = gw + (size_t)c * NEXP;
    float4 g0 = *(const float4*)(g);
    float4 g1 = *(const float4*)(g + 4);
    acc[0] += xv * g0.x; acc[1] += xv * g0.y; acc[2] += xv * g0.z; acc[3] += xv * g0.w;
    acc[4] += xv * g1.x; acc[5] += xv * g1.y; acc[6] += xv * g1.z; acc[7] += xv * g1.w;
  }
#pragma unroll
  for (int off = 32; off > 0; off >>= 1) {
#pragma unroll
    for (int e = 0; e < NEXP; ++e) acc[e] += __shfl_xor(acc[e], off, 64);
  }
  int e0 = 0; float l0 = acc[0];
#pragma unroll
  for (int e = 1; e < NEXP; ++e) { if (acc[e] > l0) { l0 = acc[e]; e0 = e; } }
  int e1 = -1; float l1 = -3.4e38f;
#pragma unroll
  for (int e = 0; e < NEXP; ++e) { if (e != e0 && acc[e] > l1) { l1 = acc[e]; e1 = e; } }
  float ex = expf(l1 - l0);
  float w0 = 1.f / (1.f + ex), w1 = ex / (1.f + ex);
  if (l < NEXP) {
    dense_w[(size_t)t * NEXP + l] = (l == e0) ? w0 : ((l == e1) ? w1 : 0.f);
    logits_out[(size_t)t * NEXP + l] = acc[l];
  }
}

template <int MODE>
__global__ __launch_bounds__(256) void gemm_bt(
    const bf16* __restrict__ A, const bf16* __restrict__ Bt,
    int K, int N,
    bf16* __restrict__ Dbf, const bf16* __restrict__ Gin,
    float* __restrict__ outAcc, const float* __restrict__ denseW, int expertId) {
  __shared__ __align__(16) bf16 sA[128 * 32];
  __shared__ __align__(16) bf16 sB[128 * 32];
  const int tid = threadIdx.x;
  const int l = tid & 63, wv = tid >> 6;
  const int wr = wv >> 1, wc = wv & 1;
  const int m0 = blockIdx.y * 128, n0 = blockIdx.x * 128;
  f32x4 acc[4][4];
#pragma unroll
  for (int i = 0; i < 4; ++i)
#pragma unroll
    for (int j = 0; j < 4; ++j) acc[i][j] = (f32x4){0.f, 0.f, 0.f, 0.f};
  const int srow = wv * 16 + (l >> 2);
  const int scol = (l & 3) * 8;
  const bf16* gA = A + (size_t)(m0 + srow) * K + scol;
  const bf16* gB = Bt + (size_t)(n0 + srow) * K + scol;
  bf16* lA = sA + srow * 32 + scol;
  bf16* lB = sB + srow * 32 + scol;
  const int fr = l & 15, fk = (l >> 4) * 8;
  const bf16* rA = sA + (size_t)(wr * 64 + fr) * 32 + fk;
  const bf16* rB = sB + (size_t)(wc * 64 + fr) * 32 + fk;
  for (int k0 = 0; k0 < K; k0 += 32) {
    __syncthreads();
    gload_lds16(gA, lA);
    gload_lds16(gA + (size_t)64 * K, lA + 64 * 32);
    gload_lds16(gB, lB);
    gload_lds16(gB + (size_t)64 * K, lB + 64 * 32);
    gA += 32; gB += 32;
    __syncthreads();
    bf16x8 af[4], bfr[4];
#pragma unroll
    for (int i = 0; i < 4; ++i) af[i] = *(const bf16x8*)(rA + i * 16 * 32);
#pragma unroll
    for (int j = 0; j < 4; ++j) bfr[j] = *(const bf16x8*)(rB + j * 16 * 32);
#pragma unroll
    for (int i = 0; i < 4; ++i)
#pragma unroll
      for (int j = 0; j < 4; ++j)
        acc[i][j] = __builtin_amdgcn_mfma_f32_16x16x32_bf16(af[i], bfr[j], acc[i][j], 0, 0, 0);
  }
  const int cn = n0 + wc * 64 + (l & 15);
  const int rb = m0 + wr * 64 + (l >> 4) * 4;
#pragma unroll
  for (int i = 0; i < 4; ++i)
#pragma unroll
    for (int r = 0; r < 4; ++r) {
      const int m = rb + i * 16 + r;
#pragma unroll
      for (int j = 0; j < 4; ++j) {
        const int n = cn + j * 16;
        float v = acc[i][j][r];
        if (MODE == 0) {
          Dbf[(size_t)m * N + n] = (bf16)v;
        } else if (MODE == 1) {
          float g = (float)Gin[(size_t)m * N + n];
          float s = g / (1.f + expf(-g));
          Dbf[(size_t)m * N + n] = (bf16)(s * v);
        } else if (MODE == 2) {
          outAcc[(size_t)m * N + n] = v;
        } else {
          float w = denseW[(size_t)m * NEXP + expertId];
          outAcc[(size_t)m * N + n] += w * v;
        }
      }
    }
}

extern "C" void kernel_launch(void* const* d_in, const int* in_sizes, int n_in,
                              void* d_out, int out_size, void* d_ws, size_t ws_size,
                              hipStream_t stream) {
  const float* x    = (const float*)d_in[0];
  const float* gate = (const float*)d_in[1];
  const float* sg   = (const float*)d_in[2];
  const float* su   = (const float*)d_in[3];
  const float* sd   = (const float*)d_in[4];
  const float* eg   = (const float*)d_in[5];
  const float* eu   = (const float*)d_in[6];
  const float* ed   = (const float*)d_in[7];
  float* out    = (float*)d_out;
  float* logits = out + (size_t)NTOK * CDIM;

  const size_t MB = 1u << 20;
  const size_t full_need = 226 * MB;

  if (ws_size >= full_need) {
    // ===== sparse top-2 path =====
    char* ws = (char*)d_ws;
    bf16*  xb   = (bf16*)(ws);                    // 16 MB
    bf16*  wTg  = (bf16*)(ws + 16 * MB);          // 36 MB (dead after gemm_gu2)
    bf16*  wTu  = (bf16*)(ws + 52 * MB);          // 36 MB (dead after gemm_gu2)
    bf16*  act  = (bf16*)(ws + 88 * MB);          // 104 MB (26624 x 2048 bf16)
    bf16*  wTd  = (bf16*)(ws + 16 * MB);          // aliases wTg (transposed after gemm_gu2)
    char*  sm   = ws + 224 * MB;
    int*   list_tok = (int*)(sm);                       // 104 KB
    int*   tk_e     = (int*)(sm + 256 * 1024);          // 64 KB
    float* tk_w     = (float*)(sm + 320 * 1024);        // 64 KB
    int*   tile_seg = (int*)(sm + 384 * 1024);          // 416 B
    int*   counts   = (int*)(sm + 388 * 1024);
    int*   fill     = (int*)(sm + 389 * 1024);
    int*   offs     = (int*)(sm + 390 * 1024);
    float* w_row    = (float*)(sm + 400 * 1024);        // 104 KB

    init_kernel<<<1, 64, 0, stream>>>(counts, fill);
    zero_out_kernel<<<NTOK * CDIM / (256 * 8), 256, 0, stream>>>(out);
    cast_x_kernel<<<NTOK * CDIM / (256 * 8), 256, 0, stream>>>(x, xb);
    router2_kernel<<<NTOK / 4, 256, 0, stream>>>(x, gate, logits, tk_e, tk_w, counts);
    offsets_kernel<<<1, 256, 0, stream>>>(counts, offs, tile_seg, list_tok, w_row);
    scatter_kernel<<<NTOK / 256, 256, 0, stream>>>(tk_e, tk_w, offs, fill, list_tok, w_row);

    dim3 tgu(HDIM / 64, CDIM / 64, 18);
    transpose_gu_kernel<<<tgu, 256, 0, stream>>>(sg, su, eg, eu, (u16*)wTg, (u16*)wTu);

    gemm_gu2<<<(HDIM / 128) * MAXTILES, 512, 0, stream>>>(xb, wTg, wTu, tile_seg, list_tok, act);

    dim3 tdd(CDIM / 64, HDIM / 64, 9);
    transpose_d_kernel<<<tdd, 256, 0, stream>>>(sd, ed, (u16*)wTd);

    gemm_down2<<<(CDIM / 128) * MAXTILES, 512, 0, stream>>>(act, wTd, tile_seg, list_tok, w_row, out);
    return;
  }

  // ===== fallback: round-2 dense path (requires ~61 MB) =====
  char* ws = (char*)d_ws;
  bf16*  xb   = (bf16*)(ws);
  bf16*  wTgf = (bf16*)(ws + 16 * MB);
  bf16*  wTuf = (bf16*)(ws + 20 * MB);
  bf16*  wTdf = (bf16*)(ws + 24 * MB);
  bf16*  gbuf = (bf16*)(ws + 28 * MB);
  float* dw   = (float*)(ws + 60 * MB);
  if (ws_size < 60 * MB + (size_t)NTOK * NEXP * sizeof(float)) return;

  cast_x_kernel<<<NTOK * CDIM / (256 * 8), 256, 0, stream>>>(x, xb);
  router_kernel<<<NTOK / 4, 256, 0, stream>>>(x, gate, dw, logits);

  dim3 tg1(HDIM / 64, CDIM / 64);
  dim3 tg2(CDIM / 64, HDIM / 64);
  dim3 g1(HDIM / 128, NTOK / 128);
  dim3 g2(CDIM / 128, NTOK / 128);

  transpose_cast_kernel<<<tg1, 256, 0, stream>>>(sg, (u16*)wTgf, CDIM, HDIM);
  transpose_cast_kernel<<<tg1, 256, 0, stream>>>(su, (u16*)wTuf, CDIM, HDIM);
  transpose_cast_kernel<<<tg2, 256, 0, stream>>>(sd, (u16*)wTdf, HDIM, CDIM);
  gemm_bt<0><<<g1, 256, 0, stream>>>(xb, wTgf, CDIM, HDIM, gbuf, nullptr, nullptr, nullptr, 0);
  gemm_bt<1><<<g1, 256, 0, stream>>>(xb, wTuf, CDIM, HDIM, gbuf, gbuf, nullptr, nullptr, 0);
  gemm_bt<2><<<g2, 256, 0, stream>>>(gbuf, wTdf, HDIM, CDIM, nullptr, nullptr, out, nullptr, 0);

  for (int e = 0; e < NEXP; ++e) {
    const float* egp = eg + (size_t)e * CDIM * HDIM;
    const float* eup = eu + (size_t)e * CDIM * HDIM;
    const float* edp = ed + (size_t)e * HDIM * CDIM;
    transpose_cast_kernel<<<tg1, 256, 0, stream>>>(egp, (u16*)wTgf, CDIM, HDIM);
    transpose_cast_kernel<<<tg1, 256, 0, stream>>>(eup, (u16*)wTuf, CDIM, HDIM);
    transpose_cast_kernel<<<tg2, 256, 0, stream>>>(edp, (u16*)wTdf, HDIM, CDIM);
    gemm_bt<0><<<g1, 256, 0, stream>>>(xb, wTgf, CDIM, HDIM, gbuf, nullptr, nullptr, nullptr, 0);
    gemm_bt<1><<<g1, 256, 0, stream>>>(xb, wTuf, CDIM, HDIM, gbuf, gbuf, nullptr, nullptr, 0);
    gemm_bt<3><<<g2, 256, 0, stream>>>(gbuf, wTdf, HDIM, CDIM, nullptr, nullptr, out, dw, e);
  }
}

// Round 3
// 970.593 us; speedup vs baseline: 1.1979x; 1.0009x over previous
//
#include <hip/hip_runtime.h>
#include <cstdint>
#include <cstddef>

// Shapes (fixed by the problem)
#define NTOK 8192   // B*T
#define CDIM 1024
#define HDIM 2048
#define NEXP 8
#define NSEG 9        // 8 routed + 1 shared
#define MAXTILES 104  // 256-row tiles: worst case 72 routed + 32 shared
#define GUTILES (MAXTILES * 2)  // 128-row tiles for gemm_gu3

typedef __bf16 bf16;
typedef unsigned short u16;
typedef __attribute__((ext_vector_type(8))) __bf16 bf16x8;
typedef __attribute__((ext_vector_type(4))) float f32x4;

__device__ __forceinline__ u16 f2bf(float f) {
  union { u16 u; __bf16 b; } cv;
  cv.b = (__bf16)f;
  return cv.u;
}

// Async global->LDS, 16B per lane. Global address may be per-lane arbitrary;
// LDS dest must be wave-uniform base + lane*16 (ours is lane-linear).
__device__ __forceinline__ void gload_lds16(const bf16* g, bf16* l) {
  __builtin_amdgcn_global_load_lds(
      (const __attribute__((address_space(1))) unsigned int*)g,
      (__attribute__((address_space(3))) unsigned int*)l, 16, 0, 0);
}

// ---------------- init control counters ----------------
__global__ __launch_bounds__(64) void init_kernel(int* __restrict__ counts,
                                                  int* __restrict__ fill) {
  if (threadIdx.x < NEXP) {
    counts[threadIdx.x] = 0;
    fill[threadIdx.x] = 0;
  }
}

// ---------------- zero the output accumulator ----------------
__global__ __launch_bounds__(256) void zero_out_kernel(float* __restrict__ out) {
  size_t i = ((size_t)blockIdx.x * 256 + threadIdx.x) * 8;
  float4 z = {0.f, 0.f, 0.f, 0.f};
  *(float4*)(out + i) = z;
  *(float4*)(out + i + 4) = z;
}

// ---------------- x: fp32 -> bf16 ----------------
__global__ __launch_bounds__(256) void cast_x_kernel(
    const float* __restrict__ src, bf16* __restrict__ dst) {
  size_t i = ((size_t)blockIdx.x * 256 + threadIdx.x) * 8;
  float4 a = *(const float4*)(src + i);
  float4 b = *(const float4*)(src + i + 4);
  bf16x8 p;
  p[0] = (bf16)a.x; p[1] = (bf16)a.y; p[2] = (bf16)a.z; p[3] = (bf16)a.w;
  p[4] = (bf16)b.x; p[5] = (bf16)b.y; p[6] = (bf16)b.z; p[7] = (bf16)b.w;
  *(bf16x8*)(dst + i) = p;
}

// ---------------- router: logits + top2 + per-expert counts ----------------
__global__ __launch_bounds__(256) void router2_kernel(
    const float* __restrict__ x, const float* __restrict__ gw,
    float* __restrict__ logits_out, int* __restrict__ tk_e,
    float* __restrict__ tk_w, int* __restrict__ counts) {
  int wv = threadIdx.x >> 6, l = threadIdx.x & 63;
  int t = blockIdx.x * 4 + wv;
  const float* xr = x + (size_t)t * CDIM;
  float acc[NEXP];
#pragma unroll
  for (int e = 0; e < NEXP; ++e) acc[e] = 0.f;
  for (int c = l; c < CDIM; c += 64) {
    float xv = xr[c];
    const float* g = gw + (size_t)c * NEXP;
    float4 g0 = *(const float4*)(g);
    float4 g1 = *(const float4*)(g + 4);
    acc[0] += xv * g0.x; acc[1] += xv * g0.y; acc[2] += xv * g0.z; acc[3] += xv * g0.w;
    acc[4] += xv * g1.x; acc[5] += xv * g1.y; acc[6] += xv * g1.z; acc[7] += xv * g1.w;
  }
#pragma unroll
  for (int off = 32; off > 0; off >>= 1) {
#pragma unroll
    for (int e = 0; e < NEXP; ++e) acc[e] += __shfl_xor(acc[e], off, 64);
  }
  int e0 = 0; float l0 = acc[0];
#pragma unroll
  for (int e = 1; e < NEXP; ++e) { if (acc[e] > l0) { l0 = acc[e]; e0 = e; } }
  int e1 = -1; float l1 = -3.4e38f;
#pragma unroll
  for (int e = 0; e < NEXP; ++e) { if (e != e0 && acc[e] > l1) { l1 = acc[e]; e1 = e; } }
  float ex = expf(l1 - l0);
  float w0 = 1.f / (1.f + ex), w1 = ex / (1.f + ex);
  if (l < NEXP) logits_out[(size_t)t * NEXP + l] = acc[l];
  if (l == 0) {
    tk_e[2 * t] = e0; tk_e[2 * t + 1] = e1;
    tk_w[2 * t] = w0; tk_w[2 * t + 1] = w1;
    atomicAdd(&counts[e0], 1);
    atomicAdd(&counts[e1], 1);
  }
}

// ---------------- segment offsets (pad 256), tile->segment map, pad fill ----------------
__global__ __launch_bounds__(256) void offsets_kernel(
    const int* __restrict__ counts, int* __restrict__ offs_g,
    int* __restrict__ tile_seg, int* __restrict__ list_tok,
    float* __restrict__ w_row) {
  __shared__ int off[NSEG], pad[NSEG], cnt[NSEG], ntot;
  int tid = threadIdx.x;
  if (tid == 0) {
    int tot = 0;
    for (int e = 0; e < NSEG; ++e) {
      int c = (e < NEXP) ? counts[e] : NTOK;
      cnt[e] = c; off[e] = tot;
      int p = (c + 255) & ~255;
      pad[e] = p; tot += p;
    }
    ntot = tot;
  }
  __syncthreads();
  if (tid < NSEG) offs_g[tid] = off[tid];
  for (int gt = tid; gt < MAXTILES; gt += 256) {
    int row = gt * 256, seg = -1;
    if (row < ntot) {
      for (int e = 0; e < NSEG; ++e)
        if (row >= off[e] && row < off[e] + pad[e]) { seg = e; break; }
    }
    tile_seg[gt] = seg;
  }
  for (int e = 0; e < NSEG; ++e)
    for (int i = off[e] + cnt[e] + tid; i < off[e] + pad[e]; i += 256) {
      list_tok[i] = 0;
      w_row[i] = 0.f;   // pad rows contribute nothing
    }
}

// ---------------- scatter tokens into compact lists + per-row combine weight ----------------
__global__ __launch_bounds__(256) void scatter_kernel(
    const int* __restrict__ tk_e, const float* __restrict__ tk_w,
    const int* __restrict__ offs, int* __restrict__ fill,
    int* __restrict__ list_tok, float* __restrict__ w_row) {
  int t = blockIdx.x * 256 + threadIdx.x;
  int e0 = tk_e[2 * t], e1 = tk_e[2 * t + 1];
  float w0 = tk_w[2 * t], w1 = tk_w[2 * t + 1];
  int p0 = atomicAdd(&fill[e0], 1);
  int i0 = offs[e0] + p0;
  list_tok[i0] = t; w_row[i0] = w0;
  int p1 = atomicAdd(&fill[e1], 1);
  int i1 = offs[e1] + p1;
  list_tok[i1] = t; w_row[i1] = w1;
  int rsh = offs[NEXP] + t;   // shared segment: identity, weight 1
  list_tok[rsh] = t; w_row[rsh] = 1.f;
}

// ---------------- transpose+cast body: fp32 RxC -> bf16 CxR ----------------
__device__ __forceinline__ void transpose_body(const float* __restrict__ src,
                                               u16* __restrict__ dst, int R, int C) {
  __shared__ u16 tile[64][65];
  int r0 = blockIdx.y * 64, c0 = blockIdx.x * 64;
  int tr = threadIdx.x >> 2;
  int tc = (threadIdx.x & 3) * 16;
  const float* s = src + (size_t)(r0 + tr) * C + c0 + tc;
  float4 f[4];
#pragma unroll
  for (int q = 0; q < 4; ++q) f[q] = *(const float4*)(s + q * 4);
#pragma unroll
  for (int q = 0; q < 4; ++q) {
    tile[tr][tc + q * 4 + 0] = f2bf(f[q].x);
    tile[tr][tc + q * 4 + 1] = f2bf(f[q].y);
    tile[tr][tc + q * 4 + 2] = f2bf(f[q].z);
    tile[tr][tc + q * 4 + 3] = f2bf(f[q].w);
  }
  __syncthreads();
  union { uint4 v[2]; u16 e[16]; } u;
#pragma unroll
  for (int j = 0; j < 16; ++j) u.e[j] = tile[tc + j][tr];
  u16* d = dst + (size_t)(c0 + tr) * R + r0 + tc;
  *(uint4*)d = u.v[0];
  *(uint4*)(d + 8) = u.v[1];
}

__global__ __launch_bounds__(256) void transpose_cast_kernel(
    const float* __restrict__ src, u16* __restrict__ dst, int R, int C) {
  transpose_body(src, dst, R, C);
}

// gate/up weights: (C,H) -> (H,C). z: 0=sg,1=su, 2..9=eg[e], 10..17=eu[e]
__global__ __launch_bounds__(256) void transpose_gu_kernel(
    const float* __restrict__ sg, const float* __restrict__ su,
    const float* __restrict__ eg, const float* __restrict__ eu,
    u16* __restrict__ wTg, u16* __restrict__ wTu) {
  const size_t slot = (size_t)HDIM * CDIM;
  int z = blockIdx.z;
  const float* src; u16* dst;
  if (z == 0)       { src = sg;                 dst = wTg + 8 * slot; }
  else if (z == 1)  { src = su;                 dst = wTu + 8 * slot; }
  else if (z < 10)  { src = eg + (z - 2) * slot;  dst = wTg + (z - 2) * slot; }
  else              { src = eu + (z - 10) * slot; dst = wTu + (z - 10) * slot; }
  transpose_body(src, dst, CDIM, HDIM);
}

// down weights: (H,C) -> (C,H). z: 0=sd, 1..8=ed[e]
__global__ __launch_bounds__(256) void transpose_d_kernel(
    const float* __restrict__ sd, const float* __restrict__ ed,
    u16* __restrict__ wTd) {
  const size_t slot = (size_t)HDIM * CDIM;
  int z = blockIdx.z;
  const float* src; u16* dst;
  if (z == 0) { src = sd;                 dst = wTd + 8 * slot; }
  else        { src = ed + (z - 1) * slot; dst = wTd + (z - 1) * slot; }
  transpose_body(src, dst, HDIM, CDIM);
}

// =====================================================================
// BK=32 double-buffered gather-GEMMs sized for 2+ blocks/CU (cross-block
// MFMA/LDS overlap, m114 mechanism). Row-paired LDS layout: two M-rows per
// 128-B LDS row; unit(m,u) = (m&1)*4 + (u ^ ((m>>1)&3)) -> 2 lanes/bank
// (conflict-free). Swizzle applied on BOTH stage-source and ds_read sides;
// gload_lds dest stays lane-linear. A+B staged as ONE contiguous region ->
// uniform 3 loads/thread/K-tile; counted gate vmcnt(3) (never 0 mid-loop).
// Per K-tile: {vmcnt; bar; ds_read frags; lgkm0; bar; stage(kt+2); MFMA}.
// =====================================================================

// ---------------- fused gate+up gather-GEMM with silu epilogue ----------------
// tile 128x128, 8 waves = 2M x 4N (wave 64x32 per GEMM-pair), acc 64 f32.
__global__ __launch_bounds__(512, 4) void gemm_gu3(
    const bf16* __restrict__ xb, const bf16* __restrict__ wTg,
    const bf16* __restrict__ wTu, const int* __restrict__ tile_seg,
    const int* __restrict__ list_tok, bf16* __restrict__ act) {
  __shared__ __align__(16) bf16 sS[2][12288];  // 24 KB/buf: A[0..8K) Bg[8K..16K) Bu[16K..24K)
  __shared__ int tokLds[128];

  const int nwg = gridDim.x;                           // 16*GUTILES, %8==0
  const int bid = blockIdx.x;
  const int wid = (bid & 7) * (nwg >> 3) + (bid >> 3); // bijective XCD chunking
  const int tileIdx = wid % GUTILES;
  const int colIdx = wid / GUTILES;
  const int seg = tile_seg[tileIdx >> 1];
  if (seg < 0) return;

  const int tid = threadIdx.x, l = tid & 63, wv = tid >> 6;
  const int wr = wv >> 2, wn = wv & 3;                 // 2 M-waves x 4 N-waves
  const int n0 = colIdx * 128;
  const size_t rowbase = (size_t)tileIdx * 128;

  if (tid < 128) tokLds[tid] = list_tok[rowbase + tid];
  __syncthreads();

  // staging: thread t covers row m=2*(t>>3)+((t>>2)&1), logical unit u=(t&3)^((t>>3)&3)
  const int srow = 2 * (tid >> 3) + ((tid >> 2) & 1);
  const int scol = (((tid & 3) ^ ((tid >> 3) & 3)) << 3);  // bf16 elems
  const bf16* gA = xb + (size_t)tokLds[srow] * CDIM + scol;
  const size_t wslot = (size_t)seg * HDIM * CDIM;
  const bf16* gBg = wTg + wslot + (size_t)(n0 + srow) * CDIM + scol;
  const bf16* gBu = wTu + wslot + (size_t)(n0 + srow) * CDIM + scol;
  const int ldst = tid * 8;  // bf16 elems

  // fragment read offsets (bytes): row-paired + swizzled
  const int fr = l & 15, u = l >> 4;
  const int laneRd = (fr >> 1) * 128 + (fr & 1) * 64 + ((u ^ ((fr >> 1) & 3)) << 4);
  const int aOff = (wr * 64) * 64 + laneRd;            // + i*1024
  const int bOff = (wn * 32) * 64 + laneRd;            // + j*1024

  f32x4 accG[4][2], accU[4][2];
#pragma unroll
  for (int i = 0; i < 4; ++i)
#pragma unroll
    for (int j = 0; j < 2; ++j) {
      accG[i][j] = (f32x4){0.f, 0.f, 0.f, 0.f};
      accU[i][j] = (f32x4){0.f, 0.f, 0.f, 0.f};
    }

  auto stage = [&](int b, int k0) {
    bf16* d = &sS[b][0] + ldst;
    gload_lds16(gA + k0, d);
    gload_lds16(gBg + k0, d + 4096);
    gload_lds16(gBu + k0, d + 8192);
  };

  constexpr int NKT = CDIM / 32;  // 32
  stage(0, 0);
  stage(1, 32);
  for (int kt = 0; kt < NKT; ++kt) {
    if (kt < NKT - 1) asm volatile("s_waitcnt vmcnt(3)" ::: "memory");
    else              asm volatile("s_waitcnt vmcnt(0)" ::: "memory");
    __builtin_amdgcn_s_barrier();
    const char* pS = (const char*)&sS[kt & 1][0];
    bf16x8 af[4], bg[2], bu[2];
#pragma unroll
    for (int i = 0; i < 4; ++i) af[i] = *(const bf16x8*)(pS + aOff + i * 1024);
#pragma unroll
    for (int j = 0; j < 2; ++j) {
      bg[j] = *(const bf16x8*)(pS + 8192 + bOff + j * 1024);
      bu[j] = *(const bf16x8*)(pS + 16384 + bOff + j * 1024);
    }
    asm volatile("s_waitcnt lgkmcnt(0)" ::: "memory");
    __builtin_amdgcn_s_barrier();
    if (kt + 2 < NKT) stage(kt & 1, (kt + 2) * 32);
    __builtin_amdgcn_s_setprio(1);
#pragma unroll
    for (int i = 0; i < 4; ++i)
#pragma unroll
      for (int j = 0; j < 2; ++j) {
        accG[i][j] = __builtin_amdgcn_mfma_f32_16x16x32_bf16(af[i], bg[j], accG[i][j], 0, 0, 0);
        accU[i][j] = __builtin_amdgcn_mfma_f32_16x16x32_bf16(af[i], bu[j], accU[i][j], 0, 0, 0);
      }
    __builtin_amdgcn_s_setprio(0);
  }

  const int cn = n0 + wn * 32 + fr;
  const int rb = wr * 64 + (l >> 4) * 4;
#pragma unroll
  for (int i = 0; i < 4; ++i)
#pragma unroll
    for (int r = 0; r < 4; ++r) {
      const size_t row = rowbase + rb + i * 16 + r;
#pragma unroll
      for (int j = 0; j < 2; ++j) {
        float g = accG[i][j][r], uu = accU[i][j][r];
        float s = g / (1.f + expf(-g));
        act[row * HDIM + cn + j * 16] = (bf16)(s * uu);
      }
    }
}

// ---------------- down-proj GEMM with fused weighted atomic combine ----------------
// tile 256x128, 8 waves = 4M x 2N (wave 64x64), acc 64 f32.
__global__ __launch_bounds__(512, 4) void gemm_down3(
    const bf16* __restrict__ act, const bf16* __restrict__ wTd,
    const int* __restrict__ tile_seg, const int* __restrict__ list_tok,
    const float* __restrict__ w_row, float* __restrict__ out) {
  __shared__ __align__(16) bf16 sS[2][12288];  // 24 KB/buf: A[0..16K) B[16K..24K)
  __shared__ int tokLds[256];
  __shared__ float wLds[256];

  const int nwg = gridDim.x;                           // 8*MAXTILES, %8==0
  const int bid = blockIdx.x;
  const int wid = (bid & 7) * (nwg >> 3) + (bid >> 3);
  const int tileIdx = wid % MAXTILES;
  const int colIdx = wid / MAXTILES;
  const int seg = tile_seg[tileIdx];
  if (seg < 0) return;

  const int tid = threadIdx.x, l = tid & 63, wv = tid >> 6;
  const int wr = wv >> 1, wc = wv & 1;
  const int n0 = colIdx * 128;
  const size_t rowbase = (size_t)tileIdx * 256;

  if (tid < 256) tokLds[tid] = list_tok[rowbase + tid];
  else           wLds[tid - 256] = w_row[rowbase + tid - 256];
  __syncthreads();

  const int srow = 2 * (tid >> 3) + ((tid >> 2) & 1);
  const int scol = (((tid & 3) ^ ((tid >> 3) & 3)) << 3);
  const bf16* gA0 = act + (rowbase + srow) * HDIM + scol;
  const bf16* gA1 = act + (rowbase + 128 + srow) * HDIM + scol;
  const bf16* gB  = wTd + (size_t)seg * CDIM * HDIM + (size_t)(n0 + srow) * HDIM + scol;
  const int ldst = tid * 8;

  const int fr = l & 15, u = l >> 4;
  const int laneRd = (fr >> 1) * 128 + (fr & 1) * 64 + ((u ^ ((fr >> 1) & 3)) << 4);
  const int aOff = (wr * 64) * 64 + laneRd;            // + i*1024
  const int bOff = 16384 + (wc * 64) * 64 + laneRd;    // + j*1024

  f32x4 acc[4][4];
#pragma unroll
  for (int i = 0; i < 4; ++i)
#pragma unroll
    for (int j = 0; j < 4; ++j) acc[i][j] = (f32x4){0.f, 0.f, 0.f, 0.f};

  auto stage = [&](int b, int k0) {
    bf16* d = &sS[b][0] + ldst;
    gload_lds16(gA0 + k0, d);
    gload_lds16(gA1 + k0, d + 4096);
    gload_lds16(gB + k0, d + 8192);
  };

  constexpr int NKT = HDIM / 32;  // 64
  stage(0, 0);
  stage(1, 32);
  for (int kt = 0; kt < NKT; ++kt) {
    if (kt < NKT - 1) asm volatile("s_waitcnt vmcnt(3)" ::: "memory");
    else              asm volatile("s_waitcnt vmcnt(0)" ::: "memory");
    __builtin_amdgcn_s_barrier();
    const char* pS = (const char*)&sS[kt & 1][0];
    bf16x8 af[4], bf[4];
#pragma unroll
    for (int i = 0; i < 4; ++i) af[i] = *(const bf16x8*)(pS + aOff + i * 1024);
#pragma unroll
    for (int j = 0; j < 4; ++j) bf[j] = *(const bf16x8*)(pS + bOff + j * 1024);
    asm volatile("s_waitcnt lgkmcnt(0)" ::: "memory");
    __builtin_amdgcn_s_barrier();
    if (kt + 2 < NKT) stage(kt & 1, (kt + 2) * 32);
    __builtin_amdgcn_s_setprio(1);
#pragma unroll
    for (int i = 0; i < 4; ++i)
#pragma unroll
      for (int j = 0; j < 4; ++j)
        acc[i][j] = __builtin_amdgcn_mfma_f32_16x16x32_bf16(af[i], bf[j], acc[i][j], 0, 0, 0);
    __builtin_amdgcn_s_setprio(0);
  }

  const int cn = n0 + wc * 64 + fr;
  const int rb = wr * 64 + (l >> 4) * 4;
#pragma unroll
  for (int i = 0; i < 4; ++i)
#pragma unroll
    for (int r = 0; r < 4; ++r) {
      const int lrow = rb + i * 16 + r;
      const float w = wLds[lrow];
      if (w != 0.f) {
        const int tok = tokLds[lrow];
        float* op = out + (size_t)tok * CDIM + cn;
#pragma unroll
        for (int j = 0; j < 4; ++j)
          atomicAdd(op + j * 16, w * acc[i][j][r]);
      }
    }
}

// ================= FALLBACK (round-2 dense path) =================
__global__ __launch_bounds__(256) void router_kernel(
    const float* __restrict__ x, const float* __restrict__ gw,
    float* __restrict__ dense_w, float* __restrict__ logits_out) {
  int wv = threadIdx.x >> 6, l = threadIdx.x & 63;
  int t = blockIdx.x * 4 + wv;
  const float* xr = x + (size_t)t * CDIM;
  float acc[NEXP];
#pragma unroll
  for (int e = 0; e < NEXP; ++e) acc[e] = 0.f;
  for (int c = l; c < CDIM; c += 64) {
    float xv = xr[c];
    const float* g = gw + (size_t)c * NEXP;
    float4 g0 = *(const float4*)(g);
    float4 g1 = *(const float4*)(g + 4);
    acc[0] += xv * g0.x; acc[1] += xv * g0.y; acc[2] += xv * g0.z; acc[3] += xv * g0.w;
    acc[4] += xv * g1.x; acc[5] += xv * g1.y; acc[6] += xv * g1.z; acc[7] += xv * g1.w;
  }
#pragma unroll
  for (int off = 32; off > 0; off >>= 1) {
#pragma unroll
    for (int e = 0; e < NEXP; ++e) acc[e] += __shfl_xor(acc[e], off, 64);
  }
  int e0 = 0; float l0 = acc[0];
#pragma unroll
  for (int e = 1; e < NEXP; ++e) { if (acc[e] > l0) { l0 = acc[e]; e0 = e; } }
  int e1 = -1; float l1 = -3.4e38f;
#pragma unroll
  for (int e = 0; e < NEXP; ++e) { if (e != e0 && acc[e] > l1) { l1 = acc[e]; e1 = e; } }
  float ex = expf(l1 - l0);
  float w0 = 1.f / (1.f + ex), w1 = ex / (1.f + ex);
  if (l < NEXP) {
    dense_w[(size_t)t * NEXP + l] = (l == e0) ? w0 : ((l == e1) ? w1 : 0.f);
    logits_out[(size_t)t * NEXP + l] = acc[l];
  }
}

template <int MODE>
__global__ __launch_bounds__(256) void gemm_bt(
    const bf16* __restrict__ A, const bf16* __restrict__ Bt,
    int K, int N,
    bf16* __restrict__ Dbf, const bf16* __restrict__ Gin,
    float* __restrict__ outAcc, const float* __restrict__ denseW, int expertId) {
  __shared__ __align__(16) bf16 sA[128 * 32];
  __shared__ __align__(16) bf16 sB[128 * 32];
  const int tid = threadIdx.x;
  const int l = tid & 63, wv = tid >> 6;
  const int wr = wv >> 1, wc = wv & 1;
  const int m0 = blockIdx.y * 128, n0 = blockIdx.x * 128;
  f32x4 acc[4][4];
#pragma unroll
  for (int i = 0; i < 4; ++i)
#pragma unroll
    for (int j = 0; j < 4; ++j) acc[i][j] = (f32x4){0.f, 0.f, 0.f, 0.f};
  const int srow = wv * 16 + (l >> 2);
  const int scol = (l & 3) * 8;
  const bf16* gA = A + (size_t)(m0 + srow) * K + scol;
  const bf16* gB = Bt + (size_t)(n0 + srow) * K + scol;
  bf16* lA = sA + srow * 32 + scol;
  bf16* lB = sB + srow * 32 + scol;
  const int fr = l & 15, fk = (l >> 4) * 8;
  const bf16* rA = sA + (size_t)(wr * 64 + fr) * 32 + fk;
  const bf16* rB = sB + (size_t)(wc * 64 + fr) * 32 + fk;
  for (int k0 = 0; k0 < K; k0 += 32) {
    __syncthreads();
    gload_lds16(gA, lA);
    gload_lds16(gA + (size_t)64 * K, lA + 64 * 32);
    gload_lds16(gB, lB);
    gload_lds16(gB + (size_t)64 * K, lB + 64 * 32);
    gA += 32; gB += 32;
    __syncthreads();
    bf16x8 af[4], bfr[4];
#pragma unroll
    for (int i = 0; i < 4; ++i) af[i] = *(const bf16x8*)(rA + i * 16 * 32);
#pragma unroll
    for (int j = 0; j < 4; ++j) bfr[j] = *(const bf16x8*)(rB + j * 16 * 32);
#pragma unroll
    for (int i = 0; i < 4; ++i)
#pragma unroll
      for (int j = 0; j < 4; ++j)
        acc[i][j] = __builtin_amdgcn_mfma_f32_16x16x32_bf16(af[i], bfr[j], acc[i][j], 0, 0, 0);
  }
  const int cn = n0 + wc * 64 + (l & 15);
  const int rb = m0 + wr * 64 + (l >> 4) * 4;
#pragma unroll
  for (int i = 0; i < 4; ++i)
#pragma unroll
    for (int r = 0; r < 4; ++r) {
      const int m = rb + i * 16 + r;
#pragma unroll
      for (int j = 0; j < 4; ++j) {
        const int n = cn + j * 16;
        float v = acc[i][j][r];
        if (MODE == 0) {
          Dbf[(size_t)m * N + n] = (bf16)v;
        } else if (MODE == 1) {
          float g = (float)Gin[(size_t)m * N + n];
          float s = g / (1.f + expf(-g));
          Dbf[(size_t)m * N + n] = (bf16)(s * v);
        } else if (MODE == 2) {
          outAcc[(size_t)m * N + n] = v;
        } else {
          float w = denseW[(size_t)m * NEXP + expertId];
          outAcc[(size_t)m * N + n] += w * v;
        }
      }
    }
}

extern "C" void kernel_launch(void* const* d_in, const int* in_sizes, int n_in,
                              void* d_out, int out_size, void* d_ws, size_t ws_size,
                              hipStream_t stream) {
  const float* x    = (const float*)d_in[0];
  const float* gate = (const float*)d_in[1];
  const float* sg   = (const float*)d_in[2];
  const float* su   = (const float*)d_in[3];
  const float* sd   = (const float*)d_in[4];
  const float* eg   = (const float*)d_in[5];
  const float* eu   = (const float*)d_in[6];
  const float* ed   = (const float*)d_in[7];
  float* out    = (float*)d_out;
  float* logits = out + (size_t)NTOK * CDIM;

  const size_t MB = 1u << 20;
  const size_t full_need = 226 * MB;

  if (ws_size >= full_need) {
    // ===== sparse top-2 path =====
    char* ws = (char*)d_ws;
    bf16*  xb   = (bf16*)(ws);                    // 16 MB
    bf16*  wTg  = (bf16*)(ws + 16 * MB);          // 36 MB (dead after gemm_gu3)
    bf16*  wTu  = (bf16*)(ws + 52 * MB);          // 36 MB (dead after gemm_gu3)
    bf16*  act  = (bf16*)(ws + 88 * MB);          // 104 MB (26624 x 2048 bf16)
    bf16*  wTd  = (bf16*)(ws + 16 * MB);          // aliases wTg (transposed after gemm_gu3)
    char*  sm   = ws + 224 * MB;
    int*   list_tok = (int*)(sm);                       // 104 KB
    int*   tk_e     = (int*)(sm + 256 * 1024);          // 64 KB
    float* tk_w     = (float*)(sm + 320 * 1024);        // 64 KB
    int*   tile_seg = (int*)(sm + 384 * 1024);          // 416 B
    int*   counts   = (int*)(sm + 388 * 1024);
    int*   fill     = (int*)(sm + 389 * 1024);
    int*   offs     = (int*)(sm + 390 * 1024);
    float* w_row    = (float*)(sm + 400 * 1024);        // 104 KB

    init_kernel<<<1, 64, 0, stream>>>(counts, fill);
    zero_out_kernel<<<NTOK * CDIM / (256 * 8), 256, 0, stream>>>(out);
    cast_x_kernel<<<NTOK * CDIM / (256 * 8), 256, 0, stream>>>(x, xb);
    router2_kernel<<<NTOK / 4, 256, 0, stream>>>(x, gate, logits, tk_e, tk_w, counts);
    offsets_kernel<<<1, 256, 0, stream>>>(counts, offs, tile_seg, list_tok, w_row);
    scatter_kernel<<<NTOK / 256, 256, 0, stream>>>(tk_e, tk_w, offs, fill, list_tok, w_row);

    dim3 tgu(HDIM / 64, CDIM / 64, 18);
    transpose_gu_kernel<<<tgu, 256, 0, stream>>>(sg, su, eg, eu, (u16*)wTg, (u16*)wTu);

    gemm_gu3<<<(HDIM / 128) * GUTILES, 512, 0, stream>>>(xb, wTg, wTu, tile_seg, list_tok, act);

    dim3 tdd(CDIM / 64, HDIM / 64, 9);
    transpose_d_kernel<<<tdd, 256, 0, stream>>>(sd, ed, (u16*)wTd);

    gemm_down3<<<(CDIM / 128) * MAXTILES, 512, 0, stream>>>(act, wTd, tile_seg, list_tok, w_row, out);
    return;
  }

  // ===== fallback: round-2 dense path (requires ~61 MB) =====
  char* ws = (char*)d_ws;
  bf16*  xb   = (bf16*)(ws);
  bf16*  wTgf = (bf16*)(ws + 16 * MB);
  bf16*  wTuf = (bf16*)(ws + 20 * MB);
  bf16*  wTdf = (bf16*)(ws + 24 * MB);
  bf16*  gbuf = (bf16*)(ws + 28 * MB);
  float* dw   = (float*)(ws + 60 * MB);
  if (ws_size < 60 * MB + (size_t)NTOK * NEXP * sizeof(float)) return;

  cast_x_kernel<<<NTOK * CDIM / (256 * 8), 256, 0, stream>>>(x, xb);
  router_kernel<<<NTOK / 4, 256, 0, stream>>>(x, gate, dw, logits);

  dim3 tg1(HDIM / 64, CDIM / 64);
  dim3 tg2(CDIM / 64, HDIM / 64);
  dim3 g1(HDIM / 128, NTOK / 128);
  dim3 g2(CDIM / 128, NTOK / 128);

  transpose_cast_kernel<<<tg1, 256, 0, stream>>>(sg, (u16*)wTgf, CDIM, HDIM);
  transpose_cast_kernel<<<tg1, 256, 0, stream>>>(su, (u16*)wTuf, CDIM, HDIM);
  transpose_cast_kernel<<<tg2, 256, 0, stream>>>(sd, (u16*)wTdf, HDIM, CDIM);
  gemm_bt<0><<<g1, 256, 0, stream>>>(xb, wTgf, CDIM, HDIM, gbuf, nullptr, nullptr, nullptr, 0);
  gemm_bt<1><<<g1, 256, 0, stream>>>(xb, wTuf, CDIM, HDIM, gbuf, gbuf, nullptr, nullptr, 0);
  gemm_bt<2><<<g2, 256, 0, stream>>>(gbuf, wTdf, HDIM, CDIM, nullptr, nullptr, out, nullptr, 0);

  for (int e = 0; e < NEXP; ++e) {
    const float* egp = eg + (size_t)e * CDIM * HDIM;
    const float* eup = eu + (size_t)e * CDIM * HDIM;
    const float* edp = ed + (size_t)e * HDIM * CDIM;
    transpose_cast_kernel<<<tg1, 256, 0, stream>>>(egp, (u16*)wTgf, CDIM, HDIM);
    transpose_cast_kernel<<<tg1, 256, 0, stream>>>(eup, (u16*)wTuf, CDIM, HDIM);
    transpose_cast_kernel<<<tg2, 256, 0, stream>>>(edp, (u16*)wTdf, HDIM, CDIM);
    gemm_bt<0><<<g1, 256, 0, stream>>>(xb, wTgf, CDIM, HDIM, gbuf, nullptr, nullptr, nullptr, 0);
    gemm_bt<1><<<g1, 256, 0, stream>>>(xb, wTuf, CDIM, HDIM, gbuf, gbuf, nullptr, nullptr, 0);
    gemm_bt<3><<<g2, 256, 0, stream>>>(gbuf, wTdf, HDIM, CDIM, nullptr, nullptr, out, dw, e);
  }
}

// Round 4
// 969.082 us; speedup vs baseline: 1.1998x; 1.0016x over previous
//
#include <hip/hip_runtime.h>
#include <cstdint>
#include <cstddef>

// Shapes (fixed by the problem)
#define NTOK 8192   // B*T
#define CDIM 1024
#define HDIM 2048
#define NEXP 8
#define NSEG 9        // 8 routed + 1 shared
#define MAXTILES 104  // 256-row tiles: worst case 72 routed + 32 shared

typedef __bf16 bf16;
typedef unsigned short u16;
typedef __attribute__((ext_vector_type(8))) __bf16 bf16x8;
typedef __attribute__((ext_vector_type(4))) float f32x4;

__device__ __forceinline__ u16 f2bf(float f) {
  union { u16 u; __bf16 b; } cv;
  cv.b = (__bf16)f;
  return cv.u;
}

// Async global->LDS, 16B per lane. Global address may be per-lane arbitrary;
// LDS dest must be wave-uniform base + lane*16 (ours is lane-linear).
__device__ __forceinline__ void gload_lds16(const bf16* g, bf16* l) {
  __builtin_amdgcn_global_load_lds(
      (const __attribute__((address_space(1))) unsigned int*)g,
      (__attribute__((address_space(3))) unsigned int*)l, 16, 0, 0);
}

// ---------------- init control counters ----------------
__global__ __launch_bounds__(64) void init_kernel(int* __restrict__ counts,
                                                  int* __restrict__ fill) {
  if (threadIdx.x < NEXP) {
    counts[threadIdx.x] = 0;
    fill[threadIdx.x] = 0;
  }
}

// ---------------- zero the output accumulator ----------------
__global__ __launch_bounds__(256) void zero_out_kernel(float* __restrict__ out) {
  size_t i = ((size_t)blockIdx.x * 256 + threadIdx.x) * 8;
  float4 z = {0.f, 0.f, 0.f, 0.f};
  *(float4*)(out + i) = z;
  *(float4*)(out + i + 4) = z;
}

// ---------------- x: fp32 -> bf16 ----------------
__global__ __launch_bounds__(256) void cast_x_kernel(
    const float* __restrict__ src, bf16* __restrict__ dst) {
  size_t i = ((size_t)blockIdx.x * 256 + threadIdx.x) * 8;
  float4 a = *(const float4*)(src + i);
  float4 b = *(const float4*)(src + i + 4);
  bf16x8 p;
  p[0] = (bf16)a.x; p[1] = (bf16)a.y; p[2] = (bf16)a.z; p[3] = (bf16)a.w;
  p[4] = (bf16)b.x; p[5] = (bf16)b.y; p[6] = (bf16)b.z; p[7] = (bf16)b.w;
  *(bf16x8*)(dst + i) = p;
}

// ---------------- router: logits + top2 + per-expert counts ----------------
__global__ __launch_bounds__(256) void router2_kernel(
    const float* __restrict__ x, const float* __restrict__ gw,
    float* __restrict__ logits_out, int* __restrict__ tk_e,
    float* __restrict__ tk_w, int* __restrict__ counts) {
  int wv = threadIdx.x >> 6, l = threadIdx.x & 63;
  int t = blockIdx.x * 4 + wv;
  const float* xr = x + (size_t)t * CDIM;
  float acc[NEXP];
#pragma unroll
  for (int e = 0; e < NEXP; ++e) acc[e] = 0.f;
  for (int c = l; c < CDIM; c += 64) {
    float xv = xr[c];
    const float* g = gw + (size_t)c * NEXP;
    float4 g0 = *(const float4*)(g);
    float4 g1 = *(const float4*)(g + 4);
    acc[0] += xv * g0.x; acc[1] += xv * g0.y; acc[2] += xv * g0.z; acc[3] += xv * g0.w;
    acc[4] += xv * g1.x; acc[5] += xv * g1.y; acc[6] += xv * g1.z; acc[7] += xv * g1.w;
  }
#pragma unroll
  for (int off = 32; off > 0; off >>= 1) {
#pragma unroll
    for (int e = 0; e < NEXP; ++e) acc[e] += __shfl_xor(acc[e], off, 64);
  }
  int e0 = 0; float l0 = acc[0];
#pragma unroll
  for (int e = 1; e < NEXP; ++e) { if (acc[e] > l0) { l0 = acc[e]; e0 = e; } }
  int e1 = -1; float l1 = -3.4e38f;
#pragma unroll
  for (int e = 0; e < NEXP; ++e) { if (e != e0 && acc[e] > l1) { l1 = acc[e]; e1 = e; } }
  float ex = expf(l1 - l0);
  float w0 = 1.f / (1.f + ex), w1 = ex / (1.f + ex);
  if (l < NEXP) logits_out[(size_t)t * NEXP + l] = acc[l];
  if (l == 0) {
    tk_e[2 * t] = e0; tk_e[2 * t + 1] = e1;
    tk_w[2 * t] = w0; tk_w[2 * t + 1] = w1;
    atomicAdd(&counts[e0], 1);
    atomicAdd(&counts[e1], 1);
  }
}

// ---------------- segment offsets (pad 256), tile->segment map, pad fill ----------------
__global__ __launch_bounds__(256) void offsets_kernel(
    const int* __restrict__ counts, int* __restrict__ offs_g,
    int* __restrict__ tile_seg, int* __restrict__ list_tok,
    float* __restrict__ w_row) {
  __shared__ int off[NSEG], pad[NSEG], cnt[NSEG], ntot;
  int tid = threadIdx.x;
  if (tid == 0) {
    int tot = 0;
    for (int e = 0; e < NSEG; ++e) {
      int c = (e < NEXP) ? counts[e] : NTOK;
      cnt[e] = c; off[e] = tot;
      int p = (c + 255) & ~255;
      pad[e] = p; tot += p;
    }
    ntot = tot;
  }
  __syncthreads();
  if (tid < NSEG) offs_g[tid] = off[tid];
  for (int gt = tid; gt < MAXTILES; gt += 256) {
    int row = gt * 256, seg = -1;
    if (row < ntot) {
      for (int e = 0; e < NSEG; ++e)
        if (row >= off[e] && row < off[e] + pad[e]) { seg = e; break; }
    }
    tile_seg[gt] = seg;
  }
  for (int e = 0; e < NSEG; ++e)
    for (int i = off[e] + cnt[e] + tid; i < off[e] + pad[e]; i += 256) {
      list_tok[i] = 0;
      w_row[i] = 0.f;   // pad rows contribute nothing
    }
}

// ---------------- scatter tokens into compact lists + per-row combine weight ----------------
__global__ __launch_bounds__(256) void scatter_kernel(
    const int* __restrict__ tk_e, const float* __restrict__ tk_w,
    const int* __restrict__ offs, int* __restrict__ fill,
    int* __restrict__ list_tok, float* __restrict__ w_row) {
  int t = blockIdx.x * 256 + threadIdx.x;
  int e0 = tk_e[2 * t], e1 = tk_e[2 * t + 1];
  float w0 = tk_w[2 * t], w1 = tk_w[2 * t + 1];
  int p0 = atomicAdd(&fill[e0], 1);
  int i0 = offs[e0] + p0;
  list_tok[i0] = t; w_row[i0] = w0;
  int p1 = atomicAdd(&fill[e1], 1);
  int i1 = offs[e1] + p1;
  list_tok[i1] = t; w_row[i1] = w1;
  int rsh = offs[NEXP] + t;   // shared segment: identity, weight 1
  list_tok[rsh] = t; w_row[rsh] = 1.f;
}

// ---------------- transpose+cast body: fp32 RxC -> bf16 CxR ----------------
__device__ __forceinline__ void transpose_body(const float* __restrict__ src,
                                               u16* __restrict__ dst, int R, int C) {
  __shared__ u16 tile[64][65];
  int r0 = blockIdx.y * 64, c0 = blockIdx.x * 64;
  int tr = threadIdx.x >> 2;
  int tc = (threadIdx.x & 3) * 16;
  const float* s = src + (size_t)(r0 + tr) * C + c0 + tc;
  float4 f[4];
#pragma unroll
  for (int q = 0; q < 4; ++q) f[q] = *(const float4*)(s + q * 4);
#pragma unroll
  for (int q = 0; q < 4; ++q) {
    tile[tr][tc + q * 4 + 0] = f2bf(f[q].x);
    tile[tr][tc + q * 4 + 1] = f2bf(f[q].y);
    tile[tr][tc + q * 4 + 2] = f2bf(f[q].z);
    tile[tr][tc + q * 4 + 3] = f2bf(f[q].w);
  }
  __syncthreads();
  union { uint4 v[2]; u16 e[16]; } u;
#pragma unroll
  for (int j = 0; j < 16; ++j) u.e[j] = tile[tc + j][tr];
  u16* d = dst + (size_t)(c0 + tr) * R + r0 + tc;
  *(uint4*)d = u.v[0];
  *(uint4*)(d + 8) = u.v[1];
}

__global__ __launch_bounds__(256) void transpose_cast_kernel(
    const float* __restrict__ src, u16* __restrict__ dst, int R, int C) {
  transpose_body(src, dst, R, C);
}

// gate/up weights: (C,H) -> (H,C). z: 0=sg,1=su, 2..9=eg[e], 10..17=eu[e]
__global__ __launch_bounds__(256) void transpose_gu_kernel(
    const float* __restrict__ sg, const float* __restrict__ su,
    const float* __restrict__ eg, const float* __restrict__ eu,
    u16* __restrict__ wTg, u16* __restrict__ wTu) {
  const size_t slot = (size_t)HDIM * CDIM;
  int z = blockIdx.z;
  const float* src; u16* dst;
  if (z == 0)       { src = sg;                 dst = wTg + 8 * slot; }
  else if (z == 1)  { src = su;                 dst = wTu + 8 * slot; }
  else if (z < 10)  { src = eg + (z - 2) * slot;  dst = wTg + (z - 2) * slot; }
  else              { src = eu + (z - 10) * slot; dst = wTu + (z - 10) * slot; }
  transpose_body(src, dst, CDIM, HDIM);
}

// down weights: (H,C) -> (C,H). z: 0=sd, 1..8=ed[e]
__global__ __launch_bounds__(256) void transpose_d_kernel(
    const float* __restrict__ sd, const float* __restrict__ ed,
    u16* __restrict__ wTd) {
  const size_t slot = (size_t)HDIM * CDIM;
  int z = blockIdx.z;
  const float* src; u16* dst;
  if (z == 0) { src = sd;                 dst = wTd + 8 * slot; }
  else        { src = ed + (z - 1) * slot; dst = wTd + (z - 1) * slot; }
  transpose_body(src, dst, HDIM, CDIM);
}

// =====================================================================
// 4-phase-per-K-tile pipelined gather-GEMMs (256-row tiles, BK=64, 8 waves
// = 2M x 4N, 1 block/CU). Per phase: {vmcnt(counted) -> barrier -> ds_read
// subtile -> issue 1 stage chunk of NEXT K-tile -> lgkmcnt(0)+sched_barrier
// -> setprio(1) -> 16 MFMA -> setprio(0)}. vmcnt never drains to 0 mid-loop
// (steady gates 4/4/4; tail peels 4/2/0). Chunk->phase map:
//   c0 = B-gate rows 0..127      (consumed phase 0)
//   c1 = A rows {0-63,128-191}   (consumed phase 0)
//   c2 = B-up  rows 0..127       (consumed phase 1)
//   c3 = A rows {64-127,192-255} (consumed phase 2)
// LDS XOR-swizzle (unit ^ row&7) on stage-source + ds_read sides; dest
// lane-linear (rule: both-sides-or-neither). 2 lanes/bank per quarter-wave.
// =====================================================================

// ---------------- fused gate+up gather-GEMM with silu epilogue ----------------
// tile 256 x (128 gate + 128 up), wave out 128x32 of each matrix.
__global__ __launch_bounds__(512, 2) void gemm_gu4(
    const bf16* __restrict__ xb, const bf16* __restrict__ wTg,
    const bf16* __restrict__ wTu, const int* __restrict__ tile_seg,
    const int* __restrict__ list_tok, bf16* __restrict__ act) {
  __shared__ __align__(16) bf16 sS[2][32768];  // 64KB/buf: A[0,16K) Bg[16K,24K) Bu[24K,32K) elems
  __shared__ int tokLds[256];

  const int nwg = gridDim.x;                           // 16*MAXTILES, %8==0
  const int bid = blockIdx.x;
  const int wid = (bid & 7) * (nwg >> 3) + (bid >> 3); // bijective XCD chunking
  const int tileIdx = wid % MAXTILES;
  const int colIdx = wid / MAXTILES;
  const int seg = tile_seg[tileIdx];
  if (seg < 0) return;

  const int tid = threadIdx.x, l = tid & 63, wv = tid >> 6;
  const int wr = wv >> 2, wn = wv & 3;                 // 2 M-waves x 4 N-waves
  const int n0 = colIdx * 128;
  const size_t rowbase = (size_t)tileIdx * 256;

  if (tid < 256) tokLds[tid] = list_tok[rowbase + tid];
  __syncthreads();

  // staging: thread t -> row8 = t>>3 within each 64-row group, k-unit pre-swizzled
  const int row8 = tid >> 3;
  const int scol = (((tid & 7) ^ (row8 & 7)) << 3);    // bf16 elems
  const bf16* gA0 = xb + (size_t)tokLds[row8] * CDIM + scol;
  const bf16* gA1 = xb + (size_t)tokLds[128 + row8] * CDIM + scol;
  const bf16* gA2 = xb + (size_t)tokLds[64 + row8] * CDIM + scol;
  const bf16* gA3 = xb + (size_t)tokLds[192 + row8] * CDIM + scol;
  const size_t wslot = (size_t)seg * HDIM * CDIM;
  const bf16* gBg = wTg + wslot + (size_t)(n0 + row8) * CDIM + scol;
  const bf16* gBu = wTu + wslot + (size_t)(n0 + row8) * CDIM + scol;
  const int t8 = tid * 8;

  // fragment read offsets (bytes)
  const int fr = l & 15, kq = l >> 4;
  const int cS0 = ((kq ^ (l & 7)) << 4);
  const int cS1 = (((4 | kq) ^ (l & 7)) << 4);
  const int aBase = (wr * 128 + fr) * 128;             // + h*8192 + i*2048
  const int gBase = 32768 + (wn * 32 + fr) * 128;      // + j*2048
  const int uBase = 49152 + (wn * 32 + fr) * 128;

  f32x4 accG[2][4][2], accU[2][4][2];
#pragma unroll
  for (int h = 0; h < 2; ++h)
#pragma unroll
    for (int i = 0; i < 4; ++i)
#pragma unroll
      for (int j = 0; j < 2; ++j) {
        accG[h][i][j] = (f32x4){0.f, 0.f, 0.f, 0.f};
        accU[h][i][j] = (f32x4){0.f, 0.f, 0.f, 0.f};
      }

  auto stC0 = [&](int b, int k0) { bf16* d = &sS[b][0];
    gload_lds16(gBg + k0, d + 16384 + t8);
    gload_lds16(gBg + 64 * CDIM + k0, d + 20480 + t8); };
  auto stC1 = [&](int b, int k0) { bf16* d = &sS[b][0];
    gload_lds16(gA0 + k0, d + t8);
    gload_lds16(gA1 + k0, d + 8192 + t8); };
  auto stC2 = [&](int b, int k0) { bf16* d = &sS[b][0];
    gload_lds16(gBu + k0, d + 24576 + t8);
    gload_lds16(gBu + 64 * CDIM + k0, d + 28672 + t8); };
  auto stC3 = [&](int b, int k0) { bf16* d = &sS[b][0];
    gload_lds16(gA2 + k0, d + 4096 + t8);
    gload_lds16(gA3 + k0, d + 12288 + t8); };

  constexpr int NKT = CDIM / 64;  // 16
  stC0(0, 0); stC1(0, 0); stC2(0, 0); stC3(0, 0);

  for (int kt = 0; kt < NKT; ++kt) {
    const int b = kt & 1, bn = b ^ 1;
    const int kn = (kt + 1) * 64;
    const bool more = (kt + 1 < NKT);
    const char* pS = (const char*)&sS[b][0];
    bf16x8 af[4][2], bg[2][2], bu[2][2];

    // ---- phase 0: h0 x G (needs c0 + c1)
    asm volatile("s_waitcnt vmcnt(4)" ::: "memory");
    __builtin_amdgcn_s_barrier();
#pragma unroll
    for (int i = 0; i < 4; ++i) {
      af[i][0] = *(const bf16x8*)(pS + aBase + i * 2048 + cS0);
      af[i][1] = *(const bf16x8*)(pS + aBase + i * 2048 + cS1);
    }
#pragma unroll
    for (int j = 0; j < 2; ++j) {
      bg[j][0] = *(const bf16x8*)(pS + gBase + j * 2048 + cS0);
      bg[j][1] = *(const bf16x8*)(pS + gBase + j * 2048 + cS1);
    }
    if (more) stC0(bn, kn);
    asm volatile("s_waitcnt lgkmcnt(0)" ::: "memory");
    __builtin_amdgcn_sched_barrier(0);
    __builtin_amdgcn_s_setprio(1);
#pragma unroll
    for (int i = 0; i < 4; ++i)
#pragma unroll
      for (int j = 0; j < 2; ++j) {
        accG[0][i][j] = __builtin_amdgcn_mfma_f32_16x16x32_bf16(af[i][0], bg[j][0], accG[0][i][j], 0, 0, 0);
        accG[0][i][j] = __builtin_amdgcn_mfma_f32_16x16x32_bf16(af[i][1], bg[j][1], accG[0][i][j], 0, 0, 0);
      }
    __builtin_amdgcn_s_setprio(0);

    // ---- phase 1: h0 x U (needs c2)
    if (more) asm volatile("s_waitcnt vmcnt(4)" ::: "memory");
    else      asm volatile("s_waitcnt vmcnt(2)" ::: "memory");
    __builtin_amdgcn_s_barrier();
#pragma unroll
    for (int j = 0; j < 2; ++j) {
      bu[j][0] = *(const bf16x8*)(pS + uBase + j * 2048 + cS0);
      bu[j][1] = *(const bf16x8*)(pS + uBase + j * 2048 + cS1);
    }
    if (more) stC1(bn, kn);
    asm volatile("s_waitcnt lgkmcnt(0)" ::: "memory");
    __builtin_amdgcn_sched_barrier(0);
    __builtin_amdgcn_s_setprio(1);
#pragma unroll
    for (int i = 0; i < 4; ++i)
#pragma unroll
      for (int j = 0; j < 2; ++j) {
        accU[0][i][j] = __builtin_amdgcn_mfma_f32_16x16x32_bf16(af[i][0], bu[j][0], accU[0][i][j], 0, 0, 0);
        accU[0][i][j] = __builtin_amdgcn_mfma_f32_16x16x32_bf16(af[i][1], bu[j][1], accU[0][i][j], 0, 0, 0);
      }
    __builtin_amdgcn_s_setprio(0);

    // ---- phase 2: h1 x G (needs c3)
    if (more) asm volatile("s_waitcnt vmcnt(4)" ::: "memory");
    else      asm volatile("s_waitcnt vmcnt(0)" ::: "memory");
    __builtin_amdgcn_s_barrier();
#pragma unroll
    for (int i = 0; i < 4; ++i) {
      af[i][0] = *(const bf16x8*)(pS + aBase + 8192 + i * 2048 + cS0);
      af[i][1] = *(const bf16x8*)(pS + aBase + 8192 + i * 2048 + cS1);
    }
    if (more) stC2(bn, kn);
    asm volatile("s_waitcnt lgkmcnt(0)" ::: "memory");
    __builtin_amdgcn_sched_barrier(0);
    __builtin_amdgcn_s_setprio(1);
#pragma unroll
    for (int i = 0; i < 4; ++i)
#pragma unroll
      for (int j = 0; j < 2; ++j) {
        accG[1][i][j] = __builtin_amdgcn_mfma_f32_16x16x32_bf16(af[i][0], bg[j][0], accG[1][i][j], 0, 0, 0);
        accG[1][i][j] = __builtin_amdgcn_mfma_f32_16x16x32_bf16(af[i][1], bg[j][1], accG[1][i][j], 0, 0, 0);
      }
    __builtin_amdgcn_s_setprio(0);

    // ---- phase 3: h1 x U (regs only)
    __builtin_amdgcn_s_barrier();
    if (more) stC3(bn, kn);
    __builtin_amdgcn_s_setprio(1);
#pragma unroll
    for (int i = 0; i < 4; ++i)
#pragma unroll
      for (int j = 0; j < 2; ++j) {
        accU[1][i][j] = __builtin_amdgcn_mfma_f32_16x16x32_bf16(af[i][0], bu[j][0], accU[1][i][j], 0, 0, 0);
        accU[1][i][j] = __builtin_amdgcn_mfma_f32_16x16x32_bf16(af[i][1], bu[j][1], accU[1][i][j], 0, 0, 0);
      }
    __builtin_amdgcn_s_setprio(0);
  }

  const int cn = n0 + wn * 32 + fr;
  const int rb = wr * 128 + kq * 4;
#pragma unroll
  for (int h = 0; h < 2; ++h)
#pragma unroll
    for (int i = 0; i < 4; ++i)
#pragma unroll
      for (int r = 0; r < 4; ++r) {
        const size_t row = rowbase + rb + h * 64 + i * 16 + r;
#pragma unroll
        for (int j = 0; j < 2; ++j) {
          float g = accG[h][i][j][r], uu = accU[h][i][j][r];
          float s = g / (1.f + expf(-g));
          act[row * HDIM + cn + j * 16] = (bf16)(s * uu);
        }
      }
}

// ---------------- down-proj GEMM with fused weighted atomic combine ----------------
// tile 256x128, wave out 128x32; 2 phases per K-tile (h0, h1).
// Chunks: c0 = B rows 0..127 (phase 0), c1 = A {0-63,128-191} (phase 0),
//         c2 = A {64-127,192-255} (phase 1). Gates: steady 2/4; tail 2/0.
__global__ __launch_bounds__(512, 2) void gemm_down4(
    const bf16* __restrict__ act, const bf16* __restrict__ wTd,
    const int* __restrict__ tile_seg, const int* __restrict__ list_tok,
    const float* __restrict__ w_row, float* __restrict__ out) {
  __shared__ __align__(16) bf16 sS[2][24576];  // 48KB/buf: A[0,16K) B[16K,24K) elems
  __shared__ int tokLds[256];
  __shared__ float wLds[256];

  const int nwg = gridDim.x;                           // 8*MAXTILES, %8==0
  const int bid = blockIdx.x;
  const int wid = (bid & 7) * (nwg >> 3) + (bid >> 3);
  const int tileIdx = wid % MAXTILES;
  const int colIdx = wid / MAXTILES;
  const int seg = tile_seg[tileIdx];
  if (seg < 0) return;

  const int tid = threadIdx.x, l = tid & 63, wv = tid >> 6;
  const int wr = wv >> 2, wn = wv & 3;                 // 2 M-waves x 4 N-waves
  const int n0 = colIdx * 128;
  const size_t rowbase = (size_t)tileIdx * 256;

  if (tid < 256) tokLds[tid] = list_tok[rowbase + tid];
  else           wLds[tid - 256] = w_row[rowbase + tid - 256];
  __syncthreads();

  const int row8 = tid >> 3;
  const int scol = (((tid & 7) ^ (row8 & 7)) << 3);
  const bf16* gA0 = act + (rowbase + row8) * HDIM + scol;
  const bf16* gA1 = act + (rowbase + 128 + row8) * HDIM + scol;
  const bf16* gA2 = act + (rowbase + 64 + row8) * HDIM + scol;
  const bf16* gA3 = act + (rowbase + 192 + row8) * HDIM + scol;
  const bf16* gB  = wTd + (size_t)seg * CDIM * HDIM + (size_t)(n0 + row8) * HDIM + scol;
  const int t8 = tid * 8;

  const int fr = l & 15, kq = l >> 4;
  const int cS0 = ((kq ^ (l & 7)) << 4);
  const int cS1 = (((4 | kq) ^ (l & 7)) << 4);
  const int aBase = (wr * 128 + fr) * 128;             // + h*8192 + i*2048
  const int bBase = 32768 + (wn * 32 + fr) * 128;      // + j*2048

  f32x4 acc[2][4][2];
#pragma unroll
  for (int h = 0; h < 2; ++h)
#pragma unroll
    for (int i = 0; i < 4; ++i)
#pragma unroll
      for (int j = 0; j < 2; ++j) acc[h][i][j] = (f32x4){0.f, 0.f, 0.f, 0.f};

  auto stC0 = [&](int b, int k0) { bf16* d = &sS[b][0];
    gload_lds16(gB + k0, d + 16384 + t8);
    gload_lds16(gB + 64 * HDIM + k0, d + 20480 + t8); };
  auto stC1 = [&](int b, int k0) { bf16* d = &sS[b][0];
    gload_lds16(gA0 + k0, d + t8);
    gload_lds16(gA1 + k0, d + 8192 + t8); };
  auto stC2 = [&](int b, int k0) { bf16* d = &sS[b][0];
    gload_lds16(gA2 + k0, d + 4096 + t8);
    gload_lds16(gA3 + k0, d + 12288 + t8); };

  constexpr int NKT = HDIM / 64;  // 32
  stC0(0, 0); stC1(0, 0); stC2(0, 0);

  for (int kt = 0; kt < NKT; ++kt) {
    const int b = kt & 1, bn = b ^ 1;
    const int kn = (kt + 1) * 64;
    const bool more = (kt + 1 < NKT);
    const char* pS = (const char*)&sS[b][0];
    bf16x8 af[4][2], bf[2][2];

    // ---- phase 0: h0 (needs c0 + c1)
    asm volatile("s_waitcnt vmcnt(2)" ::: "memory");
    __builtin_amdgcn_s_barrier();
#pragma unroll
    for (int i = 0; i < 4; ++i) {
      af[i][0] = *(const bf16x8*)(pS + aBase + i * 2048 + cS0);
      af[i][1] = *(const bf16x8*)(pS + aBase + i * 2048 + cS1);
    }
#pragma unroll
    for (int j = 0; j < 2; ++j) {
      bf[j][0] = *(const bf16x8*)(pS + bBase + j * 2048 + cS0);
      bf[j][1] = *(const bf16x8*)(pS + bBase + j * 2048 + cS1);
    }
    if (more) { stC0(bn, kn); stC1(bn, kn); }
    asm volatile("s_waitcnt lgkmcnt(0)" ::: "memory");
    __builtin_amdgcn_sched_barrier(0);
    __builtin_amdgcn_s_setprio(1);
#pragma unroll
    for (int i = 0; i < 4; ++i)
#pragma unroll
      for (int j = 0; j < 2; ++j) {
        acc[0][i][j] = __builtin_amdgcn_mfma_f32_16x16x32_bf16(af[i][0], bf[j][0], acc[0][i][j], 0, 0, 0);
        acc[0][i][j] = __builtin_amdgcn_mfma_f32_16x16x32_bf16(af[i][1], bf[j][1], acc[0][i][j], 0, 0, 0);
      }
    __builtin_amdgcn_s_setprio(0);

    // ---- phase 1: h1 (needs c2)
    if (more) asm volatile("s_waitcnt vmcnt(4)" ::: "memory");
    else      asm volatile("s_waitcnt vmcnt(0)" ::: "memory");
    __builtin_amdgcn_s_barrier();
#pragma unroll
    for (int i = 0; i < 4; ++i) {
      af[i][0] = *(const bf16x8*)(pS + aBase + 8192 + i * 2048 + cS0);
      af[i][1] = *(const bf16x8*)(pS + aBase + 8192 + i * 2048 + cS1);
    }
    if (more) stC2(bn, kn);
    asm volatile("s_waitcnt lgkmcnt(0)" ::: "memory");
    __builtin_amdgcn_sched_barrier(0);
    __builtin_amdgcn_s_setprio(1);
#pragma unroll
    for (int i = 0; i < 4; ++i)
#pragma unroll
      for (int j = 0; j < 2; ++j) {
        acc[1][i][j] = __builtin_amdgcn_mfma_f32_16x16x32_bf16(af[i][0], bf[j][0], acc[1][i][j], 0, 0, 0);
        acc[1][i][j] = __builtin_amdgcn_mfma_f32_16x16x32_bf16(af[i][1], bf[j][1], acc[1][i][j], 0, 0, 0);
      }
    __builtin_amdgcn_s_setprio(0);
  }

  const int cn = n0 + wn * 32 + fr;
  const int rb = wr * 128 + kq * 4;
#pragma unroll
  for (int h = 0; h < 2; ++h)
#pragma unroll
    for (int i = 0; i < 4; ++i)
#pragma unroll
      for (int r = 0; r < 4; ++r) {
        const int lrow = rb + h * 64 + i * 16 + r;
        const float w = wLds[lrow];
        if (w != 0.f) {
          const int tok = tokLds[lrow];
          float* op = out + (size_t)tok * CDIM + cn;
#pragma unroll
          for (int j = 0; j < 2; ++j)
            atomicAdd(op + j * 16, w * acc[h][i][j][r]);
        }
      }
}

// ================= FALLBACK (round-2 dense path) =================
__global__ __launch_bounds__(256) void router_kernel(
    const float* __restrict__ x, const float* __restrict__ gw,
    float* __restrict__ dense_w, float* __restrict__ logits_out) {
  int wv = threadIdx.x >> 6, l = threadIdx.x & 63;
  int t = blockIdx.x * 4 + wv;
  const float* xr = x + (size_t)t * CDIM;
  float acc[NEXP];
#pragma unroll
  for (int e = 0; e < NEXP; ++e) acc[e] = 0.f;
  for (int c = l; c < CDIM; c += 64) {
    float xv = xr[c];
    const float* g = gw + (size_t)c * NEXP;
    float4 g0 = *(const float4*)(g);
    float4 g1 = *(const float4*)(g + 4);
    acc[0] += xv * g0.x; acc[1] += xv * g0.y; acc[2] += xv * g0.z; acc[3] += xv * g0.w;
    acc[4] += xv * g1.x; acc[5] += xv * g1.y; acc[6] += xv * g1.z; acc[7] += xv * g1.w;
  }
#pragma unroll
  for (int off = 32; off > 0; off >>= 1) {
#pragma unroll
    for (int e = 0; e < NEXP; ++e) acc[e] += __shfl_xor(acc[e], off, 64);
  }
  int e0 = 0; float l0 = acc[0];
#pragma unroll
  for (int e = 1; e < NEXP; ++e) { if (acc[e] > l0) { l0 = acc[e]; e0 = e; } }
  int e1 = -1; float l1 = -3.4e38f;
#pragma unroll
  for (int e = 0; e < NEXP; ++e) { if (e != e0 && acc[e] > l1) { l1 = acc[e]; e1 = e; } }
  float ex = expf(l1 - l0);
  float w0 = 1.f / (1.f + ex), w1 = ex / (1.f + ex);
  if (l < NEXP) {
    dense_w[(size_t)t * NEXP + l] = (l == e0) ? w0 : ((l == e1) ? w1 : 0.f);
    logits_out[(size_t)t * NEXP + l] = acc[l];
  }
}

template <int MODE>
__global__ __launch_bounds__(256) void gemm_bt(
    const bf16* __restrict__ A, const bf16* __restrict__ Bt,
    int K, int N,
    bf16* __restrict__ Dbf, const bf16* __restrict__ Gin,
    float* __restrict__ outAcc, const float* __restrict__ denseW, int expertId) {
  __shared__ __align__(16) bf16 sA[128 * 32];
  __shared__ __align__(16) bf16 sB[128 * 32];
  const int tid = threadIdx.x;
  const int l = tid & 63, wv = tid >> 6;
  const int wr = wv >> 1, wc = wv & 1;
  const int m0 = blockIdx.y * 128, n0 = blockIdx.x * 128;
  f32x4 acc[4][4];
#pragma unroll
  for (int i = 0; i < 4; ++i)
#pragma unroll
    for (int j = 0; j < 4; ++j) acc[i][j] = (f32x4){0.f, 0.f, 0.f, 0.f};
  const int srow = wv * 16 + (l >> 2);
  const int scol = (l & 3) * 8;
  const bf16* gA = A + (size_t)(m0 + srow) * K + scol;
  const bf16* gB = Bt + (size_t)(n0 + srow) * K + scol;
  bf16* lA = sA + srow * 32 + scol;
  bf16* lB = sB + srow * 32 + scol;
  const int fr = l & 15, fk = (l >> 4) * 8;
  const bf16* rA = sA + (size_t)(wr * 64 + fr) * 32 + fk;
  const bf16* rB = sB + (size_t)(wc * 64 + fr) * 32 + fk;
  for (int k0 = 0; k0 < K; k0 += 32) {
    __syncthreads();
    gload_lds16(gA, lA);
    gload_lds16(gA + (size_t)64 * K, lA + 64 * 32);
    gload_lds16(gB, lB);
    gload_lds16(gB + (size_t)64 * K, lB + 64 * 32);
    gA += 32; gB += 32;
    __syncthreads();
    bf16x8 af[4], bfr[4];
#pragma unroll
    for (int i = 0; i < 4; ++i) af[i] = *(const bf16x8*)(rA + i * 16 * 32);
#pragma unroll
    for (int j = 0; j < 4; ++j) bfr[j] = *(const bf16x8*)(rB + j * 16 * 32);
#pragma unroll
    for (int i = 0; i < 4; ++i)
#pragma unroll
      for (int j = 0; j < 4; ++j)
        acc[i][j] = __builtin_amdgcn_mfma_f32_16x16x32_bf16(af[i], bfr[j], acc[i][j], 0, 0, 0);
  }
  const int cn = n0 + wc * 64 + (l & 15);
  const int rb = m0 + wr * 64 + (l >> 4) * 4;
#pragma unroll
  for (int i = 0; i < 4; ++i)
#pragma unroll
    for (int r = 0; r < 4; ++r) {
      const int m = rb + i * 16 + r;
#pragma unroll
      for (int j = 0; j < 4; ++j) {
        const int n = cn + j * 16;
        float v = acc[i][j][r];
        if (MODE == 0) {
          Dbf[(size_t)m * N + n] = (bf16)v;
        } else if (MODE == 1) {
          float g = (float)Gin[(size_t)m * N + n];
          float s = g / (1.f + expf(-g));
          Dbf[(size_t)m * N + n] = (bf16)(s * v);
        } else if (MODE == 2) {
          outAcc[(size_t)m * N + n] = v;
        } else {
          float w = denseW[(size_t)m * NEXP + expertId];
          outAcc[(size_t)m * N + n] += w * v;
        }
      }
    }
}

extern "C" void kernel_launch(void* const* d_in, const int* in_sizes, int n_in,
                              void* d_out, int out_size, void* d_ws, size_t ws_size,
                              hipStream_t stream) {
  const float* x    = (const float*)d_in[0];
  const float* gate = (const float*)d_in[1];
  const float* sg   = (const float*)d_in[2];
  const float* su   = (const float*)d_in[3];
  const float* sd   = (const float*)d_in[4];
  const float* eg   = (const float*)d_in[5];
  const float* eu   = (const float*)d_in[6];
  const float* ed   = (const float*)d_in[7];
  float* out    = (float*)d_out;
  float* logits = out + (size_t)NTOK * CDIM;

  const size_t MB = 1u << 20;
  const size_t full_need = 226 * MB;

  if (ws_size >= full_need) {
    // ===== sparse top-2 path =====
    char* ws = (char*)d_ws;
    bf16*  xb   = (bf16*)(ws);                    // 16 MB
    bf16*  wTg  = (bf16*)(ws + 16 * MB);          // 36 MB (dead after gemm_gu4)
    bf16*  wTu  = (bf16*)(ws + 52 * MB);          // 36 MB (dead after gemm_gu4)
    bf16*  act  = (bf16*)(ws + 88 * MB);          // 104 MB (26624 x 2048 bf16)
    bf16*  wTd  = (bf16*)(ws + 16 * MB);          // aliases wTg (transposed after gemm_gu4)
    char*  sm   = ws + 224 * MB;
    int*   list_tok = (int*)(sm);                       // 104 KB
    int*   tk_e     = (int*)(sm + 256 * 1024);          // 64 KB
    float* tk_w     = (float*)(sm + 320 * 1024);        // 64 KB
    int*   tile_seg = (int*)(sm + 384 * 1024);          // 416 B
    int*   counts   = (int*)(sm + 388 * 1024);
    int*   fill     = (int*)(sm + 389 * 1024);
    int*   offs     = (int*)(sm + 390 * 1024);
    float* w_row    = (float*)(sm + 400 * 1024);        // 104 KB

    init_kernel<<<1, 64, 0, stream>>>(counts, fill);
    zero_out_kernel<<<NTOK * CDIM / (256 * 8), 256, 0, stream>>>(out);
    cast_x_kernel<<<NTOK * CDIM / (256 * 8), 256, 0, stream>>>(x, xb);
    router2_kernel<<<NTOK / 4, 256, 0, stream>>>(x, gate, logits, tk_e, tk_w, counts);
    offsets_kernel<<<1, 256, 0, stream>>>(counts, offs, tile_seg, list_tok, w_row);
    scatter_kernel<<<NTOK / 256, 256, 0, stream>>>(tk_e, tk_w, offs, fill, list_tok, w_row);

    dim3 tgu(HDIM / 64, CDIM / 64, 18);
    transpose_gu_kernel<<<tgu, 256, 0, stream>>>(sg, su, eg, eu, (u16*)wTg, (u16*)wTu);

    gemm_gu4<<<(HDIM / 128) * MAXTILES, 512, 0, stream>>>(xb, wTg, wTu, tile_seg, list_tok, act);

    dim3 tdd(CDIM / 64, HDIM / 64, 9);
    transpose_d_kernel<<<tdd, 256, 0, stream>>>(sd, ed, (u16*)wTd);

    gemm_down4<<<(CDIM / 128) * MAXTILES, 512, 0, stream>>>(act, wTd, tile_seg, list_tok, w_row, out);
    return;
  }

  // ===== fallback: round-2 dense path (requires ~61 MB) =====
  char* ws = (char*)d_ws;
  bf16*  xb   = (bf16*)(ws);
  bf16*  wTgf = (bf16*)(ws + 16 * MB);
  bf16*  wTuf = (bf16*)(ws + 20 * MB);
  bf16*  wTdf = (bf16*)(ws + 24 * MB);
  bf16*  gbuf = (bf16*)(ws + 28 * MB);
  float* dw   = (float*)(ws + 60 * MB);
  if (ws_size < 60 * MB + (size_t)NTOK * NEXP * sizeof(float)) return;

  cast_x_kernel<<<NTOK * CDIM / (256 * 8), 256, 0, stream>>>(x, xb);
  router_kernel<<<NTOK / 4, 256, 0, stream>>>(x, gate, dw, logits);

  dim3 tg1(HDIM / 64, CDIM / 64);
  dim3 tg2(CDIM / 64, HDIM / 64);
  dim3 g1(HDIM / 128, NTOK / 128);
  dim3 g2(CDIM / 128, NTOK / 128);

  transpose_cast_kernel<<<tg1, 256, 0, stream>>>(sg, (u16*)wTgf, CDIM, HDIM);
  transpose_cast_kernel<<<tg1, 256, 0, stream>>>(su, (u16*)wTuf, CDIM, HDIM);
  transpose_cast_kernel<<<tg2, 256, 0, stream>>>(sd, (u16*)wTdf, HDIM, CDIM);
  gemm_bt<0><<<g1, 256, 0, stream>>>(xb, wTgf, CDIM, HDIM, gbuf, nullptr, nullptr, nullptr, 0);
  gemm_bt<1><<<g1, 256, 0, stream>>>(xb, wTuf, CDIM, HDIM, gbuf, gbuf, nullptr, nullptr, 0);
  gemm_bt<2><<<g2, 256, 0, stream>>>(gbuf, wTdf, HDIM, CDIM, nullptr, nullptr, out, nullptr, 0);

  for (int e = 0; e < NEXP; ++e) {
    const float* egp = eg + (size_t)e * CDIM * HDIM;
    const float* eup = eu + (size_t)e * CDIM * HDIM;
    const float* edp = ed + (size_t)e * HDIM * CDIM;
    transpose_cast_kernel<<<tg1, 256, 0, stream>>>(egp, (u16*)wTgf, CDIM, HDIM);
    transpose_cast_kernel<<<tg1, 256, 0, stream>>>(eup, (u16*)wTuf, CDIM, HDIM);
    transpose_cast_kernel<<<tg2, 256, 0, stream>>>(edp, (u16*)wTdf, HDIM, CDIM);
    gemm_bt<0><<<g1, 256, 0, stream>>>(xb, wTgf, CDIM, HDIM, gbuf, nullptr, nullptr, nullptr, 0);
    gemm_bt<1><<<g1, 256, 0, stream>>>(xb, wTuf, CDIM, HDIM, gbuf, gbuf, nullptr, nullptr, 0);
    gemm_bt<3><<<g2, 256, 0, stream>>>(gbuf, wTdf, HDIM, CDIM, nullptr, nullptr, out, dw, e);
  }
}

// Round 5
// 917.793 us; speedup vs baseline: 1.2668x; 1.0559x over previous
//
#include <hip/hip_runtime.h>
#include <cstdint>
#include <cstddef>

// Shapes (fixed by the problem)
#define NTOK 8192   // B*T
#define CDIM 1024
#define HDIM 2048
#define NEXP 8
#define NSEG 9        // 8 routed + 1 shared
#define MAXTILES 104  // 256-row tiles: worst case 72 routed + 32 shared

typedef __bf16 bf16;
typedef unsigned short u16;
typedef __attribute__((ext_vector_type(8))) __bf16 bf16x8;
typedef __attribute__((ext_vector_type(4))) float f32x4;

__device__ __forceinline__ u16 f2bf(float f) {
  union { u16 u; __bf16 b; } cv;
  cv.b = (__bf16)f;
  return cv.u;
}

// Async global->LDS, 16B per lane. Global address may be per-lane arbitrary;
// LDS dest must be wave-uniform base + lane*16 (ours is lane-linear).
__device__ __forceinline__ void gload_lds16(const bf16* g, bf16* l) {
  __builtin_amdgcn_global_load_lds(
      (const __attribute__((address_space(1))) unsigned int*)g,
      (__attribute__((address_space(3))) unsigned int*)l, 16, 0, 0);
}

// ---------------- init control counters ----------------
__global__ __launch_bounds__(64) void init_kernel(int* __restrict__ counts,
                                                  int* __restrict__ fill) {
  if (threadIdx.x < NEXP) {
    counts[threadIdx.x] = 0;
    fill[threadIdx.x] = 0;
  }
}

// ---------------- x: fp32 -> bf16 ----------------
__global__ __launch_bounds__(256) void cast_x_kernel(
    const float* __restrict__ src, bf16* __restrict__ dst) {
  size_t i = ((size_t)blockIdx.x * 256 + threadIdx.x) * 8;
  float4 a = *(const float4*)(src + i);
  float4 b = *(const float4*)(src + i + 4);
  bf16x8 p;
  p[0] = (bf16)a.x; p[1] = (bf16)a.y; p[2] = (bf16)a.z; p[3] = (bf16)a.w;
  p[4] = (bf16)b.x; p[5] = (bf16)b.y; p[6] = (bf16)b.z; p[7] = (bf16)b.w;
  *(bf16x8*)(dst + i) = p;
}

// ---------------- router: logits + top2 + per-expert counts ----------------
__global__ __launch_bounds__(256) void router2_kernel(
    const float* __restrict__ x, const float* __restrict__ gw,
    float* __restrict__ logits_out, int* __restrict__ tk_e,
    float* __restrict__ tk_w, int* __restrict__ counts) {
  int wv = threadIdx.x >> 6, l = threadIdx.x & 63;
  int t = blockIdx.x * 4 + wv;
  const float* xr = x + (size_t)t * CDIM;
  float acc[NEXP];
#pragma unroll
  for (int e = 0; e < NEXP; ++e) acc[e] = 0.f;
  for (int c = l; c < CDIM; c += 64) {
    float xv = xr[c];
    const float* g = gw + (size_t)c * NEXP;
    float4 g0 = *(const float4*)(g);
    float4 g1 = *(const float4*)(g + 4);
    acc[0] += xv * g0.x; acc[1] += xv * g0.y; acc[2] += xv * g0.z; acc[3] += xv * g0.w;
    acc[4] += xv * g1.x; acc[5] += xv * g1.y; acc[6] += xv * g1.z; acc[7] += xv * g1.w;
  }
#pragma unroll
  for (int off = 32; off > 0; off >>= 1) {
#pragma unroll
    for (int e = 0; e < NEXP; ++e) acc[e] += __shfl_xor(acc[e], off, 64);
  }
  int e0 = 0; float l0 = acc[0];
#pragma unroll
  for (int e = 1; e < NEXP; ++e) { if (acc[e] > l0) { l0 = acc[e]; e0 = e; } }
  int e1 = -1; float l1 = -3.4e38f;
#pragma unroll
  for (int e = 0; e < NEXP; ++e) { if (e != e0 && acc[e] > l1) { l1 = acc[e]; e1 = e; } }
  float ex = expf(l1 - l0);
  float w0 = 1.f / (1.f + ex), w1 = ex / (1.f + ex);
  if (l < NEXP) logits_out[(size_t)t * NEXP + l] = acc[l];
  if (l == 0) {
    tk_e[2 * t] = e0; tk_e[2 * t + 1] = e1;
    tk_w[2 * t] = w0; tk_w[2 * t + 1] = w1;
    atomicAdd(&counts[e0], 1);
    atomicAdd(&counts[e1], 1);
  }
}

// ---------------- segment offsets (pad 256), tile->segment map, pad fill ----------------
__global__ __launch_bounds__(256) void offsets_kernel(
    const int* __restrict__ counts, int* __restrict__ offs_g,
    int* __restrict__ tile_seg, int* __restrict__ list_tok) {
  __shared__ int off[NSEG], pad[NSEG], cnt[NSEG], ntot;
  int tid = threadIdx.x;
  if (tid == 0) {
    int tot = 0;
    for (int e = 0; e < NSEG; ++e) {
      int c = (e < NEXP) ? counts[e] : NTOK;
      cnt[e] = c; off[e] = tot;
      int p = (c + 255) & ~255;
      pad[e] = p; tot += p;
    }
    ntot = tot;
  }
  __syncthreads();
  if (tid < NSEG) offs_g[tid] = off[tid];
  for (int gt = tid; gt < MAXTILES; gt += 256) {
    int row = gt * 256, seg = -1;
    if (row < ntot) {
      for (int e = 0; e < NSEG; ++e)
        if (row >= off[e] && row < off[e] + pad[e]) { seg = e; break; }
    }
    tile_seg[gt] = seg;
  }
  for (int e = 0; e < NSEG; ++e)
    for (int i = off[e] + cnt[e] + tid; i < off[e] + pad[e]; i += 256)
      list_tok[i] = 0;   // pad rows: harmless token 0, never combined
}

// ---------------- scatter tokens into compact lists + inverse map ----------------
__global__ __launch_bounds__(256) void scatter_kernel(
    const int* __restrict__ tk_e, const int* __restrict__ offs,
    int* __restrict__ fill, int* __restrict__ list_tok,
    int* __restrict__ inv) {
  int t = blockIdx.x * 256 + threadIdx.x;
  int e0 = tk_e[2 * t], e1 = tk_e[2 * t + 1];
  int p0 = atomicAdd(&fill[e0], 1);
  int i0 = offs[e0] + p0;
  list_tok[i0] = t; inv[2 * t] = i0;
  int p1 = atomicAdd(&fill[e1], 1);
  int i1 = offs[e1] + p1;
  list_tok[i1] = t; inv[2 * t + 1] = i1;
  list_tok[offs[NEXP] + t] = t;  // shared segment: identity
}

// ---------------- transpose+cast body: fp32 RxC -> bf16 CxR ----------------
// Vectorized paired-row layout: t32[c][rp] (stride 33 u32) holds rows {2rp,2rp+1}
// packed as one u32. Phase 1: 4x float4 in, 8x ds_write_b32 (2-way banks, free).
// Phase 2: 8x u32 reads (compiler pairs to ds_read2_b32, 2-way banks), 32B out.
// 0.375 LDS-ops/element vs 1.25 in the old scalar-u16 gather version.
__device__ __forceinline__ void transpose_body(const float* __restrict__ src,
                                               u16* __restrict__ dst, int R, int C) {
  __shared__ uint32_t t32[64 * 33];
  const int tid = threadIdx.x;
  const int r0 = blockIdx.y * 64, c0 = blockIdx.x * 64;
  // phase 1: rows {2rp, 2rp+1}, cols [8cg, 8cg+8)
  const int rp = tid >> 3;          // 0..31
  const int cg = tid & 7;           // 0..7
  const float* s0 = src + (size_t)(r0 + 2 * rp) * C + c0 + 8 * cg;
  const float* s1 = s0 + C;
  float4 a0 = *(const float4*)(s0);
  float4 a1 = *(const float4*)(s0 + 4);
  float4 b0 = *(const float4*)(s1);
  float4 b1 = *(const float4*)(s1 + 4);
  uint32_t p[8];
  p[0] = f2bf(a0.x) | ((uint32_t)f2bf(b0.x) << 16);
  p[1] = f2bf(a0.y) | ((uint32_t)f2bf(b0.y) << 16);
  p[2] = f2bf(a0.z) | ((uint32_t)f2bf(b0.z) << 16);
  p[3] = f2bf(a0.w) | ((uint32_t)f2bf(b0.w) << 16);
  p[4] = f2bf(a1.x) | ((uint32_t)f2bf(b1.x) << 16);
  p[5] = f2bf(a1.y) | ((uint32_t)f2bf(b1.y) << 16);
  p[6] = f2bf(a1.z) | ((uint32_t)f2bf(b1.z) << 16);
  p[7] = f2bf(a1.w) | ((uint32_t)f2bf(b1.w) << 16);
#pragma unroll
  for (int c = 0; c < 8; ++c) t32[(8 * cg + c) * 33 + rp] = p[c];
  __syncthreads();
  // phase 2: output col c0+oc, rows [r0+16og, r0+16og+16)
  const int oc = tid >> 2, og = tid & 3;
  const uint32_t* rb = &t32[oc * 33 + 8 * og];
  union { uint32_t w[8]; uint4 v[2]; } u;
#pragma unroll
  for (int k = 0; k < 8; ++k) u.w[k] = rb[k];
  u16* d = dst + (size_t)(c0 + oc) * R + r0 + 16 * og;
  *(uint4*)d = u.v[0];
  *(uint4*)(d + 8) = u.v[1];
}

__global__ __launch_bounds__(256) void transpose_cast_kernel(
    const float* __restrict__ src, u16* __restrict__ dst, int R, int C) {
  transpose_body(src, dst, R, C);
}

// gate/up weights: (C,H) -> (H,C). z: 0=sg,1=su, 2..9=eg[e], 10..17=eu[e]
__global__ __launch_bounds__(256) void transpose_gu_kernel(
    const float* __restrict__ sg, const float* __restrict__ su,
    const float* __restrict__ eg, const float* __restrict__ eu,
    u16* __restrict__ wTg, u16* __restrict__ wTu) {
  const size_t slot = (size_t)HDIM * CDIM;
  int z = blockIdx.z;
  const float* src; u16* dst;
  if (z == 0)       { src = sg;                 dst = wTg + 8 * slot; }
  else if (z == 1)  { src = su;                 dst = wTu + 8 * slot; }
  else if (z < 10)  { src = eg + (z - 2) * slot;  dst = wTg + (z - 2) * slot; }
  else              { src = eu + (z - 10) * slot; dst = wTu + (z - 10) * slot; }
  transpose_body(src, dst, CDIM, HDIM);
}

// down weights: (H,C) -> (C,H). z: 0=sd, 1..8=ed[e]
__global__ __launch_bounds__(256) void transpose_d_kernel(
    const float* __restrict__ sd, const float* __restrict__ ed,
    u16* __restrict__ wTd) {
  const size_t slot = (size_t)HDIM * CDIM;
  int z = blockIdx.z;
  const float* src; u16* dst;
  if (z == 0) { src = sd;                 dst = wTd + 8 * slot; }
  else        { src = ed + (z - 1) * slot; dst = wTd + (z - 1) * slot; }
  transpose_body(src, dst, HDIM, CDIM);
}

// =====================================================================
// 4-phase-per-K-tile pipelined gather-GEMMs (256-row tiles, BK=64, 8 waves
// = 2M x 4N, 1 block/CU). Counted vmcnt, never 0 mid-loop. LDS XOR-swizzle
// (unit ^ row&7) on stage-source + ds_read sides; dest lane-linear.
// =====================================================================

// ---------------- fused gate+up gather-GEMM with silu epilogue ----------------
__global__ __launch_bounds__(512, 2) void gemm_gu4(
    const bf16* __restrict__ xb, const bf16* __restrict__ wTg,
    const bf16* __restrict__ wTu, const int* __restrict__ tile_seg,
    const int* __restrict__ list_tok, bf16* __restrict__ act) {
  __shared__ __align__(16) bf16 sS[2][32768];  // 64KB/buf: A[0,16K) Bg[16K,24K) Bu[24K,32K) elems
  __shared__ int tokLds[256];

  const int nwg = gridDim.x;                           // 16*MAXTILES, %8==0
  const int bid = blockIdx.x;
  const int wid = (bid & 7) * (nwg >> 3) + (bid >> 3); // bijective XCD chunking
  const int tileIdx = wid % MAXTILES;
  const int colIdx = wid / MAXTILES;
  const int seg = tile_seg[tileIdx];
  if (seg < 0) return;

  const int tid = threadIdx.x, l = tid & 63, wv = tid >> 6;
  const int wr = wv >> 2, wn = wv & 3;                 // 2 M-waves x 4 N-waves
  const int n0 = colIdx * 128;
  const size_t rowbase = (size_t)tileIdx * 256;

  if (tid < 256) tokLds[tid] = list_tok[rowbase + tid];
  __syncthreads();

  const int row8 = tid >> 3;
  const int scol = (((tid & 7) ^ (row8 & 7)) << 3);    // bf16 elems
  const bf16* gA0 = xb + (size_t)tokLds[row8] * CDIM + scol;
  const bf16* gA1 = xb + (size_t)tokLds[128 + row8] * CDIM + scol;
  const bf16* gA2 = xb + (size_t)tokLds[64 + row8] * CDIM + scol;
  const bf16* gA3 = xb + (size_t)tokLds[192 + row8] * CDIM + scol;
  const size_t wslot = (size_t)seg * HDIM * CDIM;
  const bf16* gBg = wTg + wslot + (size_t)(n0 + row8) * CDIM + scol;
  const bf16* gBu = wTu + wslot + (size_t)(n0 + row8) * CDIM + scol;
  const int t8 = tid * 8;

  const int fr = l & 15, kq = l >> 4;
  const int cS0 = ((kq ^ (l & 7)) << 4);
  const int cS1 = (((4 | kq) ^ (l & 7)) << 4);
  const int aBase = (wr * 128 + fr) * 128;             // + h*8192 + i*2048
  const int gBase = 32768 + (wn * 32 + fr) * 128;      // + j*2048
  const int uBase = 49152 + (wn * 32 + fr) * 128;

  f32x4 accG[2][4][2], accU[2][4][2];
#pragma unroll
  for (int h = 0; h < 2; ++h)
#pragma unroll
    for (int i = 0; i < 4; ++i)
#pragma unroll
      for (int j = 0; j < 2; ++j) {
        accG[h][i][j] = (f32x4){0.f, 0.f, 0.f, 0.f};
        accU[h][i][j] = (f32x4){0.f, 0.f, 0.f, 0.f};
      }

  auto stC0 = [&](int b, int k0) { bf16* d = &sS[b][0];
    gload_lds16(gBg + k0, d + 16384 + t8);
    gload_lds16(gBg + 64 * CDIM + k0, d + 20480 + t8); };
  auto stC1 = [&](int b, int k0) { bf16* d = &sS[b][0];
    gload_lds16(gA0 + k0, d + t8);
    gload_lds16(gA1 + k0, d + 8192 + t8); };
  auto stC2 = [&](int b, int k0) { bf16* d = &sS[b][0];
    gload_lds16(gBu + k0, d + 24576 + t8);
    gload_lds16(gBu + 64 * CDIM + k0, d + 28672 + t8); };
  auto stC3 = [&](int b, int k0) { bf16* d = &sS[b][0];
    gload_lds16(gA2 + k0, d + 4096 + t8);
    gload_lds16(gA3 + k0, d + 12288 + t8); };

  constexpr int NKT = CDIM / 64;  // 16
  stC0(0, 0); stC1(0, 0); stC2(0, 0); stC3(0, 0);

  for (int kt = 0; kt < NKT; ++kt) {
    const int b = kt & 1, bn = b ^ 1;
    const int kn = (kt + 1) * 64;
    const bool more = (kt + 1 < NKT);
    const char* pS = (const char*)&sS[b][0];
    bf16x8 af[4][2], bg[2][2], bu[2][2];

    // ---- phase 0: h0 x G (needs c0 + c1)
    asm volatile("s_waitcnt vmcnt(4)" ::: "memory");
    __builtin_amdgcn_s_barrier();
#pragma unroll
    for (int i = 0; i < 4; ++i) {
      af[i][0] = *(const bf16x8*)(pS + aBase + i * 2048 + cS0);
      af[i][1] = *(const bf16x8*)(pS + aBase + i * 2048 + cS1);
    }
#pragma unroll
    for (int j = 0; j < 2; ++j) {
      bg[j][0] = *(const bf16x8*)(pS + gBase + j * 2048 + cS0);
      bg[j][1] = *(const bf16x8*)(pS + gBase + j * 2048 + cS1);
    }
    if (more) stC0(bn, kn);
    asm volatile("s_waitcnt lgkmcnt(0)" ::: "memory");
    __builtin_amdgcn_sched_barrier(0);
    __builtin_amdgcn_s_setprio(1);
#pragma unroll
    for (int i = 0; i < 4; ++i)
#pragma unroll
      for (int j = 0; j < 2; ++j) {
        accG[0][i][j] = __builtin_amdgcn_mfma_f32_16x16x32_bf16(af[i][0], bg[j][0], accG[0][i][j], 0, 0, 0);
        accG[0][i][j] = __builtin_amdgcn_mfma_f32_16x16x32_bf16(af[i][1], bg[j][1], accG[0][i][j], 0, 0, 0);
      }
    __builtin_amdgcn_s_setprio(0);

    // ---- phase 1: h0 x U (needs c2)
    if (more) asm volatile("s_waitcnt vmcnt(4)" ::: "memory");
    else      asm volatile("s_waitcnt vmcnt(2)" ::: "memory");
    __builtin_amdgcn_s_barrier();
#pragma unroll
    for (int j = 0; j < 2; ++j) {
      bu[j][0] = *(const bf16x8*)(pS + uBase + j * 2048 + cS0);
      bu[j][1] = *(const bf16x8*)(pS + uBase + j * 2048 + cS1);
    }
    if (more) stC1(bn, kn);
    asm volatile("s_waitcnt lgkmcnt(0)" ::: "memory");
    __builtin_amdgcn_sched_barrier(0);
    __builtin_amdgcn_s_setprio(1);
#pragma unroll
    for (int i = 0; i < 4; ++i)
#pragma unroll
      for (int j = 0; j < 2; ++j) {
        accU[0][i][j] = __builtin_amdgcn_mfma_f32_16x16x32_bf16(af[i][0], bu[j][0], accU[0][i][j], 0, 0, 0);
        accU[0][i][j] = __builtin_amdgcn_mfma_f32_16x16x32_bf16(af[i][1], bu[j][1], accU[0][i][j], 0, 0, 0);
      }
    __builtin_amdgcn_s_setprio(0);

    // ---- phase 2: h1 x G (needs c3)
    if (more) asm volatile("s_waitcnt vmcnt(4)" ::: "memory");
    else      asm volatile("s_waitcnt vmcnt(0)" ::: "memory");
    __builtin_amdgcn_s_barrier();
#pragma unroll
    for (int i = 0; i < 4; ++i) {
      af[i][0] = *(const bf16x8*)(pS + aBase + 8192 + i * 2048 + cS0);
      af[i][1] = *(const bf16x8*)(pS + aBase + 8192 + i * 2048 + cS1);
    }
    if (more) stC2(bn, kn);
    asm volatile("s_waitcnt lgkmcnt(0)" ::: "memory");
    __builtin_amdgcn_sched_barrier(0);
    __builtin_amdgcn_s_setprio(1);
#pragma unroll
    for (int i = 0; i < 4; ++i)
#pragma unroll
      for (int j = 0; j < 2; ++j) {
        accG[1][i][j] = __builtin_amdgcn_mfma_f32_16x16x32_bf16(af[i][0], bg[j][0], accG[1][i][j], 0, 0, 0);
        accG[1][i][j] = __builtin_amdgcn_mfma_f32_16x16x32_bf16(af[i][1], bg[j][1], accG[1][i][j], 0, 0, 0);
      }
    __builtin_amdgcn_s_setprio(0);

    // ---- phase 3: h1 x U (regs only)
    __builtin_amdgcn_s_barrier();
    if (more) stC3(bn, kn);
    __builtin_amdgcn_s_setprio(1);
#pragma unroll
    for (int i = 0; i < 4; ++i)
#pragma unroll
      for (int j = 0; j < 2; ++j) {
        accU[1][i][j] = __builtin_amdgcn_mfma_f32_16x16x32_bf16(af[i][0], bu[j][0], accU[1][i][j], 0, 0, 0);
        accU[1][i][j] = __builtin_amdgcn_mfma_f32_16x16x32_bf16(af[i][1], bu[j][1], accU[1][i][j], 0, 0, 0);
      }
    __builtin_amdgcn_s_setprio(0);
  }

  const int cn = n0 + wn * 32 + fr;
  const int rb = wr * 128 + kq * 4;
#pragma unroll
  for (int h = 0; h < 2; ++h)
#pragma unroll
    for (int i = 0; i < 4; ++i)
#pragma unroll
      for (int r = 0; r < 4; ++r) {
        const size_t row = rowbase + rb + h * 64 + i * 16 + r;
#pragma unroll
        for (int j = 0; j < 2; ++j) {
          float g = accG[h][i][j][r], uu = accU[h][i][j][r];
          float s = g / (1.f + expf(-g));
          act[row * HDIM + cn + j * 16] = (bf16)(s * uu);
        }
      }
}

// ---------------- down-proj GEMM: plain bf16 row store (no atomics) ----------------
// tile 256x128, wave out 128x32; 2 phases per K-tile (h0, h1).
__global__ __launch_bounds__(512, 2) void gemm_down4(
    const bf16* __restrict__ act, const bf16* __restrict__ wTd,
    const int* __restrict__ tile_seg, bf16* __restrict__ dbuf) {
  __shared__ __align__(16) bf16 sS[2][24576];  // 48KB/buf: A[0,16K) B[16K,24K) elems

  const int nwg = gridDim.x;                           // 8*MAXTILES, %8==0
  const int bid = blockIdx.x;
  const int wid = (bid & 7) * (nwg >> 3) + (bid >> 3);
  const int tileIdx = wid % MAXTILES;
  const int colIdx = wid / MAXTILES;
  const int seg = tile_seg[tileIdx];
  if (seg < 0) return;

  const int tid = threadIdx.x, l = tid & 63, wv = tid >> 6;
  const int wr = wv >> 2, wn = wv & 3;                 // 2 M-waves x 4 N-waves
  const int n0 = colIdx * 128;
  const size_t rowbase = (size_t)tileIdx * 256;

  const int row8 = tid >> 3;
  const int scol = (((tid & 7) ^ (row8 & 7)) << 3);
  const bf16* gA0 = act + (rowbase + row8) * HDIM + scol;
  const bf16* gA1 = act + (rowbase + 128 + row8) * HDIM + scol;
  const bf16* gA2 = act + (rowbase + 64 + row8) * HDIM + scol;
  const bf16* gA3 = act + (rowbase + 192 + row8) * HDIM + scol;
  const bf16* gB  = wTd + (size_t)seg * CDIM * HDIM + (size_t)(n0 + row8) * HDIM + scol;
  const int t8 = tid * 8;

  const int fr = l & 15, kq = l >> 4;
  const int cS0 = ((kq ^ (l & 7)) << 4);
  const int cS1 = (((4 | kq) ^ (l & 7)) << 4);
  const int aBase = (wr * 128 + fr) * 128;             // + h*8192 + i*2048
  const int bBase = 32768 + (wn * 32 + fr) * 128;      // + j*2048

  f32x4 acc[2][4][2];
#pragma unroll
  for (int h = 0; h < 2; ++h)
#pragma unroll
    for (int i = 0; i < 4; ++i)
#pragma unroll
      for (int j = 0; j < 2; ++j) acc[h][i][j] = (f32x4){0.f, 0.f, 0.f, 0.f};

  auto stC0 = [&](int b, int k0) { bf16* d = &sS[b][0];
    gload_lds16(gB + k0, d + 16384 + t8);
    gload_lds16(gB + 64 * HDIM + k0, d + 20480 + t8); };
  auto stC1 = [&](int b, int k0) { bf16* d = &sS[b][0];
    gload_lds16(gA0 + k0, d + t8);
    gload_lds16(gA1 + k0, d + 8192 + t8); };
  auto stC2 = [&](int b, int k0) { bf16* d = &sS[b][0];
    gload_lds16(gA2 + k0, d + 4096 + t8);
    gload_lds16(gA3 + k0, d + 12288 + t8); };

  constexpr int NKT = HDIM / 64;  // 32
  stC0(0, 0); stC1(0, 0); stC2(0, 0);

  for (int kt = 0; kt < NKT; ++kt) {
    const int b = kt & 1, bn = b ^ 1;
    const int kn = (kt + 1) * 64;
    const bool more = (kt + 1 < NKT);
    const char* pS = (const char*)&sS[b][0];
    bf16x8 af[4][2], bf[2][2];

    // ---- phase 0: h0 (needs c0 + c1)
    asm volatile("s_waitcnt vmcnt(2)" ::: "memory");
    __builtin_amdgcn_s_barrier();
#pragma unroll
    for (int i = 0; i < 4; ++i) {
      af[i][0] = *(const bf16x8*)(pS + aBase + i * 2048 + cS0);
      af[i][1] = *(const bf16x8*)(pS + aBase + i * 2048 + cS1);
    }
#pragma unroll
    for (int j = 0; j < 2; ++j) {
      bf[j][0] = *(const bf16x8*)(pS + bBase + j * 2048 + cS0);
      bf[j][1] = *(const bf16x8*)(pS + bBase + j * 2048 + cS1);
    }
    if (more) { stC0(bn, kn); stC1(bn, kn); }
    asm volatile("s_waitcnt lgkmcnt(0)" ::: "memory");
    __builtin_amdgcn_sched_barrier(0);
    __builtin_amdgcn_s_setprio(1);
#pragma unroll
    for (int i = 0; i < 4; ++i)
#pragma unroll
      for (int j = 0; j < 2; ++j) {
        acc[0][i][j] = __builtin_amdgcn_mfma_f32_16x16x32_bf16(af[i][0], bf[j][0], acc[0][i][j], 0, 0, 0);
        acc[0][i][j] = __builtin_amdgcn_mfma_f32_16x16x32_bf16(af[i][1], bf[j][1], acc[0][i][j], 0, 0, 0);
      }
    __builtin_amdgcn_s_setprio(0);

    // ---- phase 1: h1 (needs c2)
    if (more) asm volatile("s_waitcnt vmcnt(4)" ::: "memory");
    else      asm volatile("s_waitcnt vmcnt(0)" ::: "memory");
    __builtin_amdgcn_s_barrier();
#pragma unroll
    for (int i = 0; i < 4; ++i) {
      af[i][0] = *(const bf16x8*)(pS + aBase + 8192 + i * 2048 + cS0);
      af[i][1] = *(const bf16x8*)(pS + aBase + 8192 + i * 2048 + cS1);
    }
    if (more) stC2(bn, kn);
    asm volatile("s_waitcnt lgkmcnt(0)" ::: "memory");
    __builtin_amdgcn_sched_barrier(0);
    __builtin_amdgcn_s_setprio(1);
#pragma unroll
    for (int i = 0; i < 4; ++i)
#pragma unroll
      for (int j = 0; j < 2; ++j) {
        acc[1][i][j] = __builtin_amdgcn_mfma_f32_16x16x32_bf16(af[i][0], bf[j][0], acc[1][i][j], 0, 0, 0);
        acc[1][i][j] = __builtin_amdgcn_mfma_f32_16x16x32_bf16(af[i][1], bf[j][1], acc[1][i][j], 0, 0, 0);
      }
    __builtin_amdgcn_s_setprio(0);
  }

  const int cn = n0 + wn * 32 + fr;
  const int rb = wr * 128 + kq * 4;
#pragma unroll
  for (int h = 0; h < 2; ++h)
#pragma unroll
    for (int i = 0; i < 4; ++i)
#pragma unroll
      for (int r = 0; r < 4; ++r) {
        const size_t row = rowbase + rb + h * 64 + i * 16 + r;
#pragma unroll
        for (int j = 0; j < 2; ++j)
          dbuf[row * CDIM + cn + j * 16] = (bf16)acc[h][i][j][r];
      }
}

// ---------------- combine: out[t] = shared + w0*d0 + w1*d1 ----------------
__global__ __launch_bounds__(128) void combine_kernel(
    const bf16* __restrict__ dbuf, const int* __restrict__ offs,
    const int* __restrict__ inv, const float* __restrict__ tk_w,
    float* __restrict__ out) {
  const int t = blockIdx.x;
  const int c = threadIdx.x * 8;
  const int rsh = offs[NEXP] + t;
  const int i0 = inv[2 * t], i1 = inv[2 * t + 1];
  const float w0 = tk_w[2 * t], w1 = tk_w[2 * t + 1];
  bf16x8 a = *(const bf16x8*)(dbuf + (size_t)rsh * CDIM + c);
  bf16x8 b = *(const bf16x8*)(dbuf + (size_t)i0 * CDIM + c);
  bf16x8 d = *(const bf16x8*)(dbuf + (size_t)i1 * CDIM + c);
  float* op = out + (size_t)t * CDIM + c;
#pragma unroll
  for (int j = 0; j < 8; ++j)
    op[j] = (float)a[j] + w0 * (float)b[j] + w1 * (float)d[j];
}

// ================= FALLBACK (round-2 dense path) =================
__global__ __launch_bounds__(256) void router_kernel(
    const float* __restrict__ x, const float* __restrict__ gw,
    float* __restrict__ dense_w, float* __restrict__ logits_out) {
  int wv = threadIdx.x >> 6, l = threadIdx.x & 63;
  int t = blockIdx.x * 4 + wv;
  const float* xr = x + (size_t)t * CDIM;
  float acc[NEXP];
#pragma unroll
  for (int e = 0; e < NEXP; ++e) acc[e] = 0.f;
  for (int c = l; c < CDIM; c += 64) {
    float xv = xr[c];
    const float* g = gw + (size_t)c * NEXP;
    float4 g0 = *(const float4*)(g);
    float4 g1 = *(const float4*)(g + 4);
    acc[0] += xv * g0.x; acc[1] += xv * g0.y; acc[2] += xv * g0.z; acc[3] += xv * g0.w;
    acc[4] += xv * g1.x; acc[5] += xv * g1.y; acc[6] += xv * g1.z; acc[7] += xv * g1.w;
  }
#pragma unroll
  for (int off = 32; off > 0; off >>= 1) {
#pragma unroll
    for (int e = 0; e < NEXP; ++e) acc[e] += __shfl_xor(acc[e], off, 64);
  }
  int e0 = 0; float l0 = acc[0];
#pragma unroll
  for (int e = 1; e < NEXP; ++e) { if (acc[e] > l0) { l0 = acc[e]; e0 = e; } }
  int e1 = -1; float l1 = -3.4e38f;
#pragma unroll
  for (int e = 0; e < NEXP; ++e) { if (e != e0 && acc[e] > l1) { l1 = acc[e]; e1 = e; } }
  float ex = expf(l1 - l0);
  float w0 = 1.f / (1.f + ex), w1 = ex / (1.f + ex);
  if (l < NEXP) {
    dense_w[(size_t)t * NEXP + l] = (l == e0) ? w0 : ((l == e1) ? w1 : 0.f);
    logits_out[(size_t)t * NEXP + l] = acc[l];
  }
}

template <int MODE>
__global__ __launch_bounds__(256) void gemm_bt(
    const bf16* __restrict__ A, const bf16* __restrict__ Bt,
    int K, int N,
    bf16* __restrict__ Dbf, const bf16* __restrict__ Gin,
    float* __restrict__ outAcc, const float* __restrict__ denseW, int expertId) {
  __shared__ __align__(16) bf16 sA[128 * 32];
  __shared__ __align__(16) bf16 sB[128 * 32];
  const int tid = threadIdx.x;
  const int l = tid & 63, wv = tid >> 6;
  const int wr = wv >> 1, wc = wv & 1;
  const int m0 = blockIdx.y * 128, n0 = blockIdx.x * 128;
  f32x4 acc[4][4];
#pragma unroll
  for (int i = 0; i < 4; ++i)
#pragma unroll
    for (int j = 0; j < 4; ++j) acc[i][j] = (f32x4){0.f, 0.f, 0.f, 0.f};
  const int srow = wv * 16 + (l >> 2);
  const int scol = (l & 3) * 8;
  const bf16* gA = A + (size_t)(m0 + srow) * K + scol;
  const bf16* gB = Bt + (size_t)(n0 + srow) * K + scol;
  bf16* lA = sA + srow * 32 + scol;
  bf16* lB = sB + srow * 32 + scol;
  const int fr = l & 15, fk = (l >> 4) * 8;
  const bf16* rA = sA + (size_t)(wr * 64 + fr) * 32 + fk;
  const bf16* rB = sB + (size_t)(wc * 64 + fr) * 32 + fk;
  for (int k0 = 0; k0 < K; k0 += 32) {
    __syncthreads();
    gload_lds16(gA, lA);
    gload_lds16(gA + (size_t)64 * K, lA + 64 * 32);
    gload_lds16(gB, lB);
    gload_lds16(gB + (size_t)64 * K, lB + 64 * 32);
    gA += 32; gB += 32;
    __syncthreads();
    bf16x8 af[4], bfr[4];
#pragma unroll
    for (int i = 0; i < 4; ++i) af[i] = *(const bf16x8*)(rA + i * 16 * 32);
#pragma unroll
    for (int j = 0; j < 4; ++j) bfr[j] = *(const bf16x8*)(rB + j * 16 * 32);
#pragma unroll
    for (int i = 0; i < 4; ++i)
#pragma unroll
      for (int j = 0; j < 4; ++j)
        acc[i][j] = __builtin_amdgcn_mfma_f32_16x16x32_bf16(af[i], bfr[j], acc[i][j], 0, 0, 0);
  }
  const int cn = n0 + wc * 64 + (l & 15);
  const int rb = m0 + wr * 64 + (l >> 4) * 4;
#pragma unroll
  for (int i = 0; i < 4; ++i)
#pragma unroll
    for (int r = 0; r < 4; ++r) {
      const int m = rb + i * 16 + r;
#pragma unroll
      for (int j = 0; j < 4; ++j) {
        const int n = cn + j * 16;
        float v = acc[i][j][r];
        if (MODE == 0) {
          Dbf[(size_t)m * N + n] = (bf16)v;
        } else if (MODE == 1) {
          float g = (float)Gin[(size_t)m * N + n];
          float s = g / (1.f + expf(-g));
          Dbf[(size_t)m * N + n] = (bf16)(s * v);
        } else if (MODE == 2) {
          outAcc[(size_t)m * N + n] = v;
        } else {
          float w = denseW[(size_t)m * NEXP + expertId];
          outAcc[(size_t)m * N + n] += w * v;
        }
      }
    }
}

extern "C" void kernel_launch(void* const* d_in, const int* in_sizes, int n_in,
                              void* d_out, int out_size, void* d_ws, size_t ws_size,
                              hipStream_t stream) {
  const float* x    = (const float*)d_in[0];
  const float* gate = (const float*)d_in[1];
  const float* sg   = (const float*)d_in[2];
  const float* su   = (const float*)d_in[3];
  const float* sd   = (const float*)d_in[4];
  const float* eg   = (const float*)d_in[5];
  const float* eu   = (const float*)d_in[6];
  const float* ed   = (const float*)d_in[7];
  float* out    = (float*)d_out;
  float* logits = out + (size_t)NTOK * CDIM;

  const size_t MB = 1u << 20;
  const size_t full_need = 226 * MB;

  if (ws_size >= full_need) {
    // ===== sparse top-2 path =====
    // Liveness plan: gu phase uses xb(0-16) wTg(16-52) wTu(52-88) act(88-192).
    // After gemm_gu4: xb/wTg/wTu dead -> wTd = 0-36, dbuf = 36-88 (52 MiB).
    char* ws = (char*)d_ws;
    bf16*  xb   = (bf16*)(ws);                    // 16 MB
    bf16*  wTg  = (bf16*)(ws + 16 * MB);          // 36 MB
    bf16*  wTu  = (bf16*)(ws + 52 * MB);          // 36 MB
    bf16*  act  = (bf16*)(ws + 88 * MB);          // 104 MB (26624 x 2048 bf16)
    bf16*  wTd  = (bf16*)(ws);                    // 36 MB, aliases xb+wTg
    bf16*  dbuf = (bf16*)(ws + 36 * MB);          // 52 MB, aliases wTg tail + wTu
    char*  sm   = ws + 200 * MB;
    int*   list_tok = (int*)(sm);                       // 104 KB
    int*   inv      = (int*)(sm + 128 * 1024);          // 64 KB
    int*   tk_e     = (int*)(sm + 256 * 1024);          // 64 KB
    float* tk_w     = (float*)(sm + 320 * 1024);        // 64 KB
    int*   tile_seg = (int*)(sm + 384 * 1024);          // 416 B
    int*   counts   = (int*)(sm + 388 * 1024);
    int*   fill     = (int*)(sm + 389 * 1024);
    int*   offs     = (int*)(sm + 390 * 1024);

    init_kernel<<<1, 64, 0, stream>>>(counts, fill);
    cast_x_kernel<<<NTOK * CDIM / (256 * 8), 256, 0, stream>>>(x, xb);
    router2_kernel<<<NTOK / 4, 256, 0, stream>>>(x, gate, logits, tk_e, tk_w, counts);
    offsets_kernel<<<1, 256, 0, stream>>>(counts, offs, tile_seg, list_tok);
    scatter_kernel<<<NTOK / 256, 256, 0, stream>>>(tk_e, offs, fill, list_tok, inv);

    dim3 tgu(HDIM / 64, CDIM / 64, 18);
    transpose_gu_kernel<<<tgu, 256, 0, stream>>>(sg, su, eg, eu, (u16*)wTg, (u16*)wTu);

    gemm_gu4<<<(HDIM / 128) * MAXTILES, 512, 0, stream>>>(xb, wTg, wTu, tile_seg, list_tok, act);

    dim3 tdd(CDIM / 64, HDIM / 64, 9);
    transpose_d_kernel<<<tdd, 256, 0, stream>>>(sd, ed, (u16*)wTd);

    gemm_down4<<<(CDIM / 128) * MAXTILES, 512, 0, stream>>>(act, wTd, tile_seg, dbuf);
    combine_kernel<<<NTOK, 128, 0, stream>>>(dbuf, offs, inv, tk_w, out);
    return;
  }

  // ===== fallback: round-2 dense path (requires ~61 MB) =====
  char* ws = (char*)d_ws;
  bf16*  xb   = (bf16*)(ws);
  bf16*  wTgf = (bf16*)(ws + 16 * MB);
  bf16*  wTuf = (bf16*)(ws + 20 * MB);
  bf16*  wTdf = (bf16*)(ws + 24 * MB);
  bf16*  gbuf = (bf16*)(ws + 28 * MB);
  float* dw   = (float*)(ws + 60 * MB);
  if (ws_size < 60 * MB + (size_t)NTOK * NEXP * sizeof(float)) return;

  cast_x_kernel<<<NTOK * CDIM / (256 * 8), 256, 0, stream>>>(x, xb);
  router_kernel<<<NTOK / 4, 256, 0, stream>>>(x, gate, dw, logits);

  dim3 tg1(HDIM / 64, CDIM / 64);
  dim3 tg2(CDIM / 64, HDIM / 64);
  dim3 g1(HDIM / 128, NTOK / 128);
  dim3 g2(CDIM / 128, NTOK / 128);

  transpose_cast_kernel<<<tg1, 256, 0, stream>>>(sg, (u16*)wTgf, CDIM, HDIM);
  transpose_cast_kernel<<<tg1, 256, 0, stream>>>(su, (u16*)wTuf, CDIM, HDIM);
  transpose_cast_kernel<<<tg2, 256, 0, stream>>>(sd, (u16*)wTdf, HDIM, CDIM);
  gemm_bt<0><<<g1, 256, 0, stream>>>(xb, wTgf, CDIM, HDIM, gbuf, nullptr, nullptr, nullptr, 0);
  gemm_bt<1><<<g1, 256, 0, stream>>>(xb, wTuf, CDIM, HDIM, gbuf, gbuf, nullptr, nullptr, 0);
  gemm_bt<2><<<g2, 256, 0, stream>>>(gbuf, wTdf, HDIM, CDIM, nullptr, nullptr, out, nullptr, 0);

  for (int e = 0; e < NEXP; ++e) {
    const float* egp = eg + (size_t)e * CDIM * HDIM;
    const float* eup = eu + (size_t)e * CDIM * HDIM;
    const float* edp = ed + (size_t)e * HDIM * CDIM;
    transpose_cast_kernel<<<tg1, 256, 0, stream>>>(egp, (u16*)wTgf, CDIM, HDIM);
    transpose_cast_kernel<<<tg1, 256, 0, stream>>>(eup, (u16*)wTuf, CDIM, HDIM);
    transpose_cast_kernel<<<tg2, 256, 0, stream>>>(edp, (u16*)wTdf, HDIM, CDIM);
    gemm_bt<0><<<g1, 256, 0, stream>>>(xb, wTgf, CDIM, HDIM, gbuf, nullptr, nullptr, nullptr, 0);
    gemm_bt<1><<<g1, 256, 0, stream>>>(xb, wTuf, CDIM, HDIM, gbuf, gbuf, nullptr, nullptr, 0);
    gemm_bt<3><<<g2, 256, 0, stream>>>(gbuf, wTdf, HDIM, CDIM, nullptr, nullptr, out, dw, e);
  }
}